// Round 11
// baseline (351.519 us; speedup 1.0000x reference)
//
#include <hip/hip_runtime.h>
#include <hip/hip_fp16.h>

#define FDIM 128
#define NGRAPH 256
#define NCLS 10
#define STATS_BLOCKS 256
#define ELLCAP 64       // ushort slots per node (128B row); max degree ~35 << 64
#define SXPITCH 136     // LDS X row pitch in halfs: 272B -> aligned
#define NSLICE 4        // feature slices of 32 (64B/node-slice) for XCD-local gathers
#define WARMB 512       // L2-warm blocks prepended to k_gather (64 per XCD)
#define FIN_NODES 64    // nodes per block in k_finish (8 waves x 8 nodes)
#define EPB 4096        // edges per histogram/scatter block (256 thr x 16)

typedef __attribute__((ext_vector_type(8))) _Float16 half8;
typedef __attribute__((ext_vector_type(4))) float floatx4;
typedef unsigned long long ull;
typedef unsigned short u16;

__device__ __forceinline__ unsigned encf(float f) {
  unsigned b = __float_as_uint(f);
  return (b & 0x80000000u) ? ~b : (b | 0x80000000u);
}
__device__ __forceinline__ float decf(unsigned u) {
  if (u == 0u) return 0.f;  // empty segment -> 0 (matches isfinite->0)
  return (u & 0x80000000u) ? __uint_as_float(u & 0x7FFFFFFFu) : __uint_as_float(~u);
}

// Hs: [NSLICE][(N+1)][32] _Float16; row N = zero sentinel. Hagg16: [NSLICE][N][32].
// S2SW: [NSLICE][N] float2. W16T: [3][128][128] (W^T fp16).
// ell16: [N][64] u16 (16-bit idx, N<65536; sentinel N; rows sentinel-padded to x4).
// Built ATOMIC-FREE via bucket counting-sort (bucket = dst>>8, LDS atomics only).

// ---------- k_bn: BN stats + batch bounds + W^T fp16 + sentinel + edge HISTOGRAM ----------
__global__ __launch_bounds__(256) void k_bn(const float* __restrict__ x,
                                            float* __restrict__ partS,
                                            float* __restrict__ partQ, int total4,
                                            const int* __restrict__ batch,
                                            int* __restrict__ gstart,
                                            int* __restrict__ gend,
                                            const float* __restrict__ gcn_w,
                                            __half* __restrict__ W16T,
                                            __half* __restrict__ H0z,
                                            __half* __restrict__ H1z,
                                            const int* __restrict__ src,
                                            const int* __restrict__ dst,
                                            int* __restrict__ histA, int E,
                                            int nbN, int nbW, int N) {
  int t = threadIdx.x;
  int nbkt = (N + 255) >> 8;
  if (blockIdx.x >= STATS_BLOCKS + nbN + nbW + 1) {
    // per-block bucket histogram of non-self edges (LDS atomics only)
    int blkH = blockIdx.x - (STATS_BLOCKS + nbN + nbW + 1);
    __shared__ int cnt[256];
    for (int i = t; i < nbkt; i += 256) cnt[i] = 0;
    __syncthreads();
    int e0 = blkH * EPB;
#pragma unroll
    for (int i = 0; i < 16; i++) {
      int e = e0 + i * 256 + t;
      if (e < E) {
        int s = src[e], d = dst[e];
        if (s != d) atomicAdd(&cnt[d >> 8], 1);
      }
    }
    __syncthreads();
    for (int i = t; i < nbkt; i += 256) histA[blkH * nbkt + i] = cnt[i];
    return;
  }
  if (blockIdx.x >= STATS_BLOCKS + nbN + nbW) {
    // zero sentinel row N of every slice of both Hs buffers
    if (t < 256) {
      int buf = t >> 7, rem = t & 127;
      int s = rem >> 5, f = rem & 31;
      __half* B = buf ? H1z : H0z;
      B[((size_t)s * (N + 1) + N) * 32 + f] = __float2half(0.f);
    }
    return;
  }
  if (blockIdx.x >= STATS_BLOCKS + nbN) {
    // WT[l][n][k] = W[l][k][n], fp16 — 3*128*128 elems
    int idx = (blockIdx.x - STATS_BLOCKS - nbN) * 256 + t;
    if (idx < 3 * FDIM * FDIM) {
      int l = idx >> 14;
      int rem = idx & 16383;
      int n = rem >> 7;
      int k = rem & 127;
      W16T[idx] = __float2half(gcn_w[l * FDIM * FDIM + k * FDIM + n]);
    }
    return;
  }
  if (blockIdx.x >= STATS_BLOCKS) {
    int e = (blockIdx.x - STATS_BLOCKS) * 256 + t;
    if (e < N) {
      int b = batch[e];
      if (e == 0 || batch[e - 1] != b) gstart[b] = e;
      if (e == N - 1) gend[b] = N;
      else if (batch[e + 1] != b) gend[b] = e + 1;
    }
    return;
  }
  __shared__ float ss[1024];
  __shared__ float sq[1024];
  float s0 = 0, s1 = 0, s2 = 0, s3 = 0, q0 = 0, q1 = 0, q2 = 0, q3 = 0;
  for (int i = blockIdx.x * 256 + t; i < total4; i += STATS_BLOCKS * 256) {
    float4 v = ((const float4*)x)[i];
    s0 += v.x; q0 += v.x * v.x;
    s1 += v.y; q1 += v.y * v.y;
    s2 += v.z; q2 += v.z * v.z;
    s3 += v.w; q3 += v.w * v.w;
  }
  int fb = (t & 31) * 4, slot = t >> 5;
  ss[slot * 128 + fb + 0] = s0; ss[slot * 128 + fb + 1] = s1;
  ss[slot * 128 + fb + 2] = s2; ss[slot * 128 + fb + 3] = s3;
  sq[slot * 128 + fb + 0] = q0; sq[slot * 128 + fb + 1] = q1;
  sq[slot * 128 + fb + 2] = q2; sq[slot * 128 + fb + 3] = q3;
  __syncthreads();
  if (t < 128) {
    float a = 0, b = 0;
    for (int s = 0; s < 8; s++) { a += ss[s * 128 + t]; b += sq[s * 128 + t]; }
    partS[blockIdx.x * 128 + t] = a;
    partQ[blockIdx.x * 128 + t] = b;
  }
}

// ---------- k_scan: per-bucket exclusive scan over blocks (one wave per bucket) ----------
__global__ __launch_bounds__(64) void k_scan(const int* __restrict__ histA,
                                             int* __restrict__ histOff,
                                             int* __restrict__ colsum,
                                             int nbH, int nbkt) {
  int bkt = blockIdx.x;
  int lane = threadIdx.x;
  int carry = 0;
  for (int c0 = 0; c0 < nbH; c0 += 64) {
    int blk = c0 + lane;
    int v = (blk < nbH) ? histA[blk * nbkt + bkt] : 0;
    int s = v;
#pragma unroll
    for (int m = 1; m < 64; m <<= 1) {
      int u = __shfl_up(s, m);
      if (lane >= m) s += u;
    }
    if (blk < nbH) histOff[blk * nbkt + bkt] = carry + s - v;
    carry += __shfl(s, 63);
  }
  if (lane == 0) colsum[bkt] = carry;
}

// ---------- k_aff: block 0 = BN affine + counts; block 1 = bucket_base scan ----------
__global__ __launch_bounds__(256) void k_aff(const float* __restrict__ partS,
                                             const float* __restrict__ partQ,
                                             const float* __restrict__ gamma,
                                             const float* __restrict__ beta,
                                             float* __restrict__ aff_a,
                                             float* __restrict__ aff_b,
                                             const int* __restrict__ gstart,
                                             const int* __restrict__ gend,
                                             float* __restrict__ countsf,
                                             const int* __restrict__ colsum,
                                             int* __restrict__ bucket_base,
                                             int nbkt, int N) {
  int t = threadIdx.x;
  if (blockIdx.x == 1) {
    __shared__ int sc[256];
    int orig = (t < nbkt) ? colsum[t] : 0;
    sc[t] = orig;
    __syncthreads();
    for (int m = 1; m < 256; m <<= 1) {
      int v = 0;
      if (t >= m) v = sc[t - m];
      __syncthreads();
      sc[t] += v;
      __syncthreads();
    }
    if (t < nbkt) bucket_base[t] = sc[t] - orig;   // exclusive
    if (t == 0) bucket_base[nbkt] = sc[255];       // total
    return;
  }
  if (t < NGRAPH) countsf[t] = fmaxf((float)(gend[t] - gstart[t]), 1.0f);
  if (t < FDIM) {
    float a = 0.f, b = 0.f;
    for (int bk = 0; bk < STATS_BLOCKS; bk++) {
      a += partS[bk * 128 + t];
      b += partQ[bk * 128 + t];
    }
    float invN = 1.0f / (float)N;
    float mu = a * invN;
    float var = b * invN - mu * mu;
    float inv = rsqrtf(var + 1e-5f);
    float ga = gamma[t] * inv;
    aff_a[t] = ga;
    aff_b[t] = beta[t] - mu * ga;
  }
}

// ---------- k_scatter: edges -> bucket-sorted packed array (LDS atomics only) ----------
__global__ __launch_bounds__(256) void k_scatter(const int* __restrict__ src,
                                                 const int* __restrict__ dst,
                                                 const int* __restrict__ histOff,
                                                 const int* __restrict__ bucket_base,
                                                 unsigned* __restrict__ bucketed,
                                                 int E, int nbkt) {
  __shared__ int off[256];
  int t = threadIdx.x;
  for (int i = t; i < nbkt; i += 256)
    off[i] = bucket_base[i] + histOff[blockIdx.x * nbkt + i];
  __syncthreads();
  int e0 = blockIdx.x * EPB;
#pragma unroll
  for (int i = 0; i < 16; i++) {
    int e = e0 + i * 256 + t;
    if (e < E) {
      int s = src[e], d = dst[e];
      if (s != d) {
        int pos = atomicAdd(&off[d >> 8], 1);
        bucketed[pos] = ((unsigned)(d & 255) << 16) | (unsigned)s;
      }
    }
  }
}

// ---------- k_build: one block per bucket -> ell16 rows + deg/dinv + sentinel pad ----------
__global__ __launch_bounds__(256) void k_build(const unsigned* __restrict__ bucketed,
                                               const int* __restrict__ bucket_base,
                                               u16* __restrict__ ell16,
                                               int* __restrict__ deg,
                                               float* __restrict__ dinv, int N) {
  __shared__ int cnt[256];
  int t = threadIdx.x;
  int b = blockIdx.x;
  cnt[t] = 0;
  __syncthreads();
  int e0 = bucket_base[b], e1 = bucket_base[b + 1];
  for (int e = e0 + t; e < e1; e += 256) {
    unsigned u = bucketed[e];
    int dlo = (int)(u >> 16);
    int s = (int)(u & 0xffffu);
    int slot = atomicAdd(&cnt[dlo], 1);
    if (slot < ELLCAP)
      ell16[(size_t)((b << 8) + dlo) * ELLCAP + slot] = (u16)s;
  }
  __syncthreads();
  int node = (b << 8) + t;
  if (node < N) {
    int d = min(cnt[t], ELLCAP);
    int pd = (d + 3) & ~3;                 // pad to 4 (one gather-iter granularity)
    deg[node] = pd;
    dinv[node] = rsqrtf(1.0f + (float)d);
    for (int j = d; j < pd; j++) ell16[(size_t)node * ELLCAP + j] = (u16)N;
  }
}

// ---------- gemm0 (MFMA): H0 = dinv * (affine(x) @ W0), sliced fp16 output ----------
__global__ __launch_bounds__(512) void k_gemm0(const float* __restrict__ x,
                                               const float* __restrict__ aff_a,
                                               const float* __restrict__ aff_b,
                                               const _Float16* __restrict__ WT,
                                               _Float16* __restrict__ Hout,
                                               const float* __restrict__ dinv,
                                               int N) {
  int t = threadIdx.x;
  __shared__ _Float16 sX[64 * SXPITCH];
  __shared__ float sDV[64];
  int nb = blockIdx.x * 64;
  if (t < 64) sDV[t] = dinv[min(nb + t, N - 1)];
#pragma unroll
  for (int i = 0; i < 4; i++) {
    int idx = i * 512 + t;          // 0..2047
    int row = idx >> 5;             // 0..63
    int c4 = idx & 31;              // float4 column
    int node = min(nb + row, N - 1);
    float4 v = *(const float4*)(x + (size_t)node * 128 + c4 * 4);
    float4 a = *(const float4*)(aff_a + c4 * 4);
    float4 b = *(const float4*)(aff_b + c4 * 4);
    __half2 h01 = __floats2half2_rn(fmaf(v.x, a.x, b.x), fmaf(v.y, a.y, b.y));
    __half2 h23 = __floats2half2_rn(fmaf(v.z, a.z, b.z), fmaf(v.w, a.w, b.w));
    uint2 st;
    st.x = *(unsigned*)&h01;
    st.y = *(unsigned*)&h23;
    *(uint2*)(sX + row * SXPITCH + c4 * 4) = st;
  }
  __syncthreads();
  int wv = t >> 6, l = t & 63;
  int r16 = l & 15, quad = l >> 4;
  int col = wv * 16 + r16;            // output feature
  int oslice = wv >> 1;
  int within = ((wv & 1) << 4) + r16; // col & 31
#pragma unroll
  for (int mt = 0; mt < 4; mt++) {
    floatx4 acc = (floatx4){0.f, 0.f, 0.f, 0.f};
#pragma unroll
    for (int ks = 0; ks < 4; ks++) {
      half8 bfrag = *(const half8*)(WT + (size_t)col * 128 + ks * 32 + quad * 8);
      half8 afrag = *(const half8*)(sX + (mt * 16 + r16) * SXPITCH + ks * 32 + quad * 8);
      acc = __builtin_amdgcn_mfma_f32_16x16x32_f16(afrag, bfrag, acc, 0, 0, 0);
    }
#pragma unroll
    for (int j = 0; j < 4; j++) {
      int row = mt * 16 + quad * 4 + j;
      int node = nb + row;
      if (node < N)
        Hout[((size_t)oslice * (N + 1) + node) * 32 + within] = (_Float16)(acc[j] * sDV[row]);
    }
  }
}

// ---------- pass A: XCD-local sliced aggregation, 8 nodes/wave, u16 idx ----------
// Lanes = nd(8 nodes) x fl(8B chunk). Each lane owns its node's 4 features COMPLETELY:
// no cross-lane merges for h. Per 4-edge iter: one uint2 idx load -> 4 INDEPENDENT
// gathers. Rows are sentinel-padded to x4 so no in-loop masking at all.
__global__ __launch_bounds__(512) void k_gather(const __half* __restrict__ Hs,
                                                __half* __restrict__ Hagg16,
                                                float2* __restrict__ S2SW,
                                                const int* __restrict__ deg,
                                                const u16* __restrict__ ell16,
                                                const float* __restrict__ bias,
                                                const float* __restrict__ watt,
                                                const float* __restrict__ dinv,
                                                int N) {
  int bid = blockIdx.x;
  int t = threadIdx.x;
  int xcd = bid & 7;
  int slice = xcd >> 1;
  if (bid < WARMB) {
    int wb = bid >> 3;                     // 0..63 within this XCD
    const float4* p = (const float4*)(Hs + (size_t)slice * (N + 1) * 32);
    size_t total = (size_t)(N + 1) * 4;    // 16B units per slice
    float acc = 0.f;
    for (size_t i = (size_t)wb * 512 + t; i < total; i += (size_t)64 * 512) {
      float4 v = p[i];
      acc += (v.x + v.y) + (v.z + v.w);
    }
    // warm this XCD's parity-half idx rows (first 64B = 32 u16 slots per node)
    int p0 = xcd & 1;
    const unsigned* e32 = (const unsigned*)ell16;
    int chunks = (N + 127) / 128;          // each (chunk,p0) covers 64 nodes
    int node_off = t >> 4, word = t & 15;  // 32 nodes x 16 uints per half
    for (int c = wb; c < chunks; c += 64) {
#pragma unroll
      for (int half = 0; half < 2; half++) {
        int node = (2 * c + p0) * 64 + half * 32 + node_off;
        if (node < N) acc += (float)(e32[(size_t)node * 32 + word] & 1u);
      }
    }
    asm volatile("" :: "v"(acc));          // keep loads alive
    return;
  }
  int gb = bid - WARMB;                    // WARMB%8==0 so gb&7 == bid&7
  int p0 = xcd & 1;
  int chunk = gb >> 3;
  int wv = t >> 6, l = t & 63;
  int nodeBase = ((chunk * 2 + p0) * 8 + wv) * 8;   // 8 nodes per wave
  if (nodeBase >= N) return;
  int nd = l >> 3;                         // node within group (0..7)
  int fl = l & 7;                          // 8B chunk (4 features) within slice
  int node = min(nodeBase + nd, N - 1);
  bool nvalid = (nodeBase + nd) < N;
  const __half* HsS = Hs + (size_t)slice * (N + 1) * 32;
  int pd = deg[node];                      // padded multiple of 4 (lane's own bound)
  float dn = dinv[node];
  size_t ebase = (size_t)node * ELLCAP;    // u16 units; 128B-aligned row
  // self row (independent; issue early)
  uint2 sv = *(const uint2*)(HsS + (size_t)node * 32 + fl * 4);
  float a0 = 0.f, a1 = 0.f, a2 = 0.f, a3 = 0.f;
#pragma unroll 2
  for (int j = 0; j < pd; j += 4) {
    uint2 u = *(const uint2*)(ell16 + ebase + j);   // 4 packed u16 idx
    int s0 = (int)(u.x & 0xffffu);
    int s1 = (int)(u.x >> 16);
    int s2 = (int)(u.y & 0xffffu);
    int s3 = (int)(u.y >> 16);
    uint2 v0 = *(const uint2*)(HsS + (size_t)s0 * 32 + fl * 4);
    uint2 v1 = *(const uint2*)(HsS + (size_t)s1 * 32 + fl * 4);
    uint2 v2 = *(const uint2*)(HsS + (size_t)s2 * 32 + fl * 4);
    uint2 v3 = *(const uint2*)(HsS + (size_t)s3 * 32 + fl * 4);
    float2 f0a = __half22float2(*(__half2*)&v0.x);
    float2 f0b = __half22float2(*(__half2*)&v0.y);
    float2 f1a = __half22float2(*(__half2*)&v1.x);
    float2 f1b = __half22float2(*(__half2*)&v1.y);
    float2 f2a = __half22float2(*(__half2*)&v2.x);
    float2 f2b = __half22float2(*(__half2*)&v2.y);
    float2 f3a = __half22float2(*(__half2*)&v3.x);
    float2 f3b = __half22float2(*(__half2*)&v3.y);
    a0 += (f0a.x + f1a.x) + (f2a.x + f3a.x);
    a1 += (f0a.y + f1a.y) + (f2a.y + f3a.y);
    a2 += (f0b.x + f1b.x) + (f2b.x + f3b.x);
    a3 += (f0b.y + f1b.y) + (f2b.y + f3b.y);
  }
  // add self once
  float2 s0f = __half22float2(*(__half2*)&sv.x);
  float2 s1f = __half22float2(*(__half2*)&sv.y);
  a0 += s0f.x; a1 += s0f.y; a2 += s1f.x; a3 += s1f.y;
  // h = dn*sum + bias for this lane's 4 features
  int gf = (slice << 5) + (fl << 2);
  float4 bb = *(const float4*)(bias + gf);
  float h0 = fmaf(dn, a0, bb.x);
  float h1 = fmaf(dn, a1, bb.y);
  float h2 = fmaf(dn, a2, bb.z);
  float h3 = fmaf(dn, a3, bb.w);
  float4 wa = *(const float4*)(watt + gf);
  float pp = h0 * h0 + h1 * h1 + h2 * h2 + h3 * h3;
  float sw = h0 * wa.x + h1 * wa.y + h2 * wa.z + h3 * wa.w;
  // reduce over the 8 fl lanes (xor 1,2,4 stay within the node's 8-lane group)
#pragma unroll
  for (int m = 1; m < 8; m <<= 1) {
    pp += __shfl_xor(pp, m);
    sw += __shfl_xor(sw, m);
  }
  if (nvalid && fl == 0)
    S2SW[(size_t)slice * N + node] = make_float2(pp, sw);   // cached store, L2 merges
  if (nvalid) {
    __half2 p01 = __floats2half2_rn(h0, h1);
    __half2 p23 = __floats2half2_rn(h2, h3);
    ull u = ((ull)*(unsigned*)&p23 << 32) | (ull)*(unsigned*)&p01;
    // [slice][node][32]: 8 fl lanes x 8B = full contiguous 64B line per node
    __builtin_nontemporal_store(u, (ull*)(Hagg16 + ((size_t)slice * N + node) * 32 + fl * 4));
  }
}

// ---------- pass B: squash + attention + partial pooling + MFMA epilogue ----------
// 64 nodes/block (8 waves x 8 nodes); 4 MFMA M-tiles (k_gemm0's epilogue shape).
template <int GEMM>
__global__ __launch_bounds__(512) void k_finish(const __half* __restrict__ Hagg16,
                                                const float2* __restrict__ S2SW,
                                                _Float16* __restrict__ HsNext,
                                                const _Float16* __restrict__ WT,
                                                const int* __restrict__ batch,
                                                const float* __restrict__ dinv,
                                                float* __restrict__ wsum,
                                                float* __restrict__ msum,
                                                unsigned* __restrict__ maxenc,
                                                float* __restrict__ wsP,
                                                float* __restrict__ msP,
                                                unsigned* __restrict__ mxP,
                                                int N) {
  __shared__ float l_ws[8][128];
  __shared__ float l_ms[8][128];
  __shared__ unsigned l_mx[8][128];
  __shared__ _Float16 sX[FIN_NODES * SXPITCH];
  int t = threadIdx.x;
  int wv = t >> 6, l = t & 63;
  int nb = blockIdx.x * FIN_NODES;
  int g0 = batch[nb];
  int fb = 2 * l;
  // lane's feature pair 2l,2l+1 lives in slice l>>4 at half2 index l&15
  size_t hoff = ((size_t)(l >> 4) * N) * 32 + (l & 15) * 2;
  float wsx = 0.f, wsy = 0.f, msx = 0.f, msy = 0.f;
  unsigned mxx = 0u, mxy = 0u;
#pragma unroll
  for (int i = 0; i < 8; i++) {
    int node = nb + wv * 8 + i;
    bool valid = node < N;
    float2 xv = make_float2(0.f, 0.f);
    float att = 0.f, dn = 0.f;
    bool own = false;
    int g = g0;
    if (valid) {
      float2 q0 = S2SW[node];
      float2 q1 = S2SW[(size_t)N + node];
      float2 q2 = S2SW[(size_t)2 * N + node];
      float2 q3 = S2SW[(size_t)3 * N + node];
      float pnorm = (q0.x + q1.x) + (q2.x + q3.x);
      float swv = (q0.y + q1.y) + (q2.y + q3.y);
      float factor = (pnorm / (1.0f + pnorm)) * rsqrtf(pnorm + 1e-8f);
      float2 h = __half22float2(*(const __half2*)(Hagg16 + hoff + (size_t)node * 32));
      xv = make_float2(h.x * factor, h.y * factor);
      att = factor * swv;
      dn = dinv[node];
      g = batch[node];
      own = (g == g0);
    }
    if (GEMM) {
      __half2 sxv = __floats2half2_rn(xv.x * dn, xv.y * dn);
      *(__half2*)(sX + (wv * 8 + i) * SXPITCH + fb) = sxv;
    }
    if (own) {
      wsx += att * xv.x; wsy += att * xv.y;
      msx += xv.x; msy += xv.y;
      unsigned ex = encf(xv.x), ey = encf(xv.y);
      mxx = mxx > ex ? mxx : ex;
      mxy = mxy > ey ? mxy : ey;
    } else if (valid) {  // rare: graph boundary inside block -> overflow atomics
      int basei = g * 128 + fb;
      atomicAdd(wsum + basei + 0, att * xv.x);
      atomicAdd(wsum + basei + 1, att * xv.y);
      atomicAdd(msum + basei + 0, xv.x);
      atomicAdd(msum + basei + 1, xv.y);
      atomicMax(maxenc + basei + 0, encf(xv.x));
      atomicMax(maxenc + basei + 1, encf(xv.y));
    }
  }
  l_ws[wv][fb] = wsx; l_ws[wv][fb + 1] = wsy;
  l_ms[wv][fb] = msx; l_ms[wv][fb + 1] = msy;
  l_mx[wv][fb] = mxx; l_mx[wv][fb + 1] = mxy;
  __syncthreads();
  if (t < 128) {
    float a = 0.f, b = 0.f;
    unsigned m = 0u;
#pragma unroll
    for (int w = 0; w < 8; w++) {
      a += l_ws[w][t];
      b += l_ms[w][t];
      unsigned v = l_mx[w][t];
      m = m > v ? m : v;
    }
    size_t pb = (size_t)blockIdx.x * 128 + t;
    wsP[pb] = a;
    msP[pb] = b;
    mxP[pb] = m;
  }
  if (GEMM) {
    int r16 = l & 15, quad = l >> 4;
    int col = wv * 16 + r16;            // global output feature
    int oslice = wv >> 1;
    int within = ((wv & 1) << 4) + r16; // col & 31
#pragma unroll
    for (int mt = 0; mt < 4; mt++) {
      floatx4 acc = (floatx4){0.f, 0.f, 0.f, 0.f};
#pragma unroll
      for (int ks = 0; ks < 4; ks++) {
        half8 bfrag = *(const half8*)(WT + (size_t)col * 128 + ks * 32 + quad * 8);
        half8 afrag = *(const half8*)(sX + (mt * 16 + r16) * SXPITCH + ks * 32 + quad * 8);
        acc = __builtin_amdgcn_mfma_f32_16x16x32_f16(afrag, bfrag, acc, 0, 0, 0);
      }
#pragma unroll
      for (int j = 0; j < 4; j++) {
        int row = mt * 16 + quad * 4 + j;
        int node = nb + row;
        if (node < N)
          HsNext[((size_t)oslice * (N + 1) + node) * 32 + within] = (_Float16)acc[j];
      }
    }
  }
}

// ---------- MLP head: per-graph reduction of block partials + log_softmax ----------
__global__ __launch_bounds__(128) void k_head(const float* __restrict__ wsum,
                                              const float* __restrict__ msum,
                                              const unsigned* __restrict__ maxenc,
                                              const float* __restrict__ countsf,
                                              const float* __restrict__ wsP,
                                              const float* __restrict__ msP,
                                              const unsigned* __restrict__ mxP,
                                              int NB,
                                              const int* __restrict__ gstart,
                                              const int* __restrict__ gend,
                                              const float* __restrict__ l1w,
                                              const float* __restrict__ l1b,
                                              const float* __restrict__ l2w,
                                              const float* __restrict__ l2b,
                                              float* __restrict__ out) {
  int g = blockIdx.x, t = threadIdx.x;
  __shared__ float rep[384];
  __shared__ float h1[128];
  __shared__ float lg[NCLS];
  int bs = (gstart[g] + FIN_NODES - 1) / FIN_NODES;
  int be = (gend[g] + FIN_NODES - 1) / FIN_NODES;  // blocks b with batch[64b]==g
  float ws = wsum[g * 128 + t];  // overflow contributions (all layers accumulated)
  float ms = msum[g * 128 + t];
  float r2 = 0.f;
  for (int lyr = 0; lyr < 3; lyr++) {
    unsigned mx = maxenc[(size_t)lyr * NGRAPH * 128 + g * 128 + t];
    const float* wp = wsP + (size_t)lyr * NB * 128;
    const float* mp = msP + (size_t)lyr * NB * 128;
    const unsigned* xp = mxP + (size_t)lyr * NB * 128;
    for (int b = bs; b < be; b++) {
      ws += wp[(size_t)b * 128 + t];
      ms += mp[(size_t)b * 128 + t];
      unsigned v = xp[(size_t)b * 128 + t];
      mx = mx > v ? mx : v;
    }
    r2 += decf(mx);
  }
  float invc = 1.0f / countsf[g];
  rep[t] = ws;
  rep[128 + t] = ms * invc;
  rep[256 + t] = r2;
  __syncthreads();
  float acc = l1b[t];
  for (int k = 0; k < 384; k++) acc = fmaf(rep[k], l1w[k * 128 + t], acc);
  h1[t] = fmaxf(acc, 0.f);
  __syncthreads();
  if (t < NCLS) {
    float a = l2b[t];
    for (int j = 0; j < 128; j++) a = fmaf(h1[j], l2w[j * NCLS + t], a);
    lg[t] = a;
  }
  __syncthreads();
  if (t < NCLS) {
    float m = lg[0];
    for (int c = 1; c < NCLS; c++) m = fmaxf(m, lg[c]);
    float s = 0.f;
    for (int c = 0; c < NCLS; c++) s += expf(lg[c] - m);
    out[g * NCLS + t] = lg[t] - m - logf(s);
  }
}

extern "C" void kernel_launch(void* const* d_in, const int* in_sizes, int n_in,
                              void* d_out, int out_size, void* d_ws, size_t ws_size,
                              hipStream_t stream) {
  const float* x      = (const float*)d_in[0];
  const int* edge     = (const int*)d_in[1];
  const int* batch    = (const int*)d_in[2];
  const float* gamma  = (const float*)d_in[3];
  const float* beta   = (const float*)d_in[4];
  const float* gcn_w  = (const float*)d_in[5];
  const float* gcn_b  = (const float*)d_in[6];
  const float* w_att  = (const float*)d_in[7];
  const float* l1w    = (const float*)d_in[8];
  const float* l1b    = (const float*)d_in[9];
  const float* l2w    = (const float*)d_in[10];
  const float* l2b    = (const float*)d_in[11];
  float* out          = (float*)d_out;

  const int N = in_sizes[0] / FDIM;   // 50000 (< 65536: u16 indices valid)
  const int E = in_sizes[1] / 2;      // 640000
  const int* esrc = edge;
  const int* edst = edge + E;

  char* w = (char*)d_ws;
  size_t off = 0;
  auto alloc = [&](size_t bytes) {
    void* p = (void*)(w + off);
    off += (bytes + 1023) & ~(size_t)1023;
    return p;
  };
  const int finishBlocks = (N + FIN_NODES - 1) / FIN_NODES;
  const int nbkt = (N + 255) >> 8;          // buckets (dst>>8), <=256
  const int nbH = (E + EPB - 1) / EPB;      // histogram/scatter blocks
  __half* H0 = (__half*)alloc((size_t)(N + 1) * FDIM * 2);  // sliced [4][(N+1)][32]
  __half* H1 = (__half*)alloc((size_t)(N + 1) * FDIM * 2);
  // zero zone start
  size_t zoff = off;
  int* gstart      = (int*)alloc(NGRAPH * 4);
  int* gend        = (int*)alloc(NGRAPH * 4);
  float* wsum      = (float*)alloc(NGRAPH * FDIM * 4);   // overflow-only
  float* msum      = (float*)alloc(NGRAPH * FDIM * 4);
  unsigned* maxenc = (unsigned*)alloc((size_t)3 * NGRAPH * FDIM * 4);
  size_t zbytes = off - zoff;
  // non-zeroed
  float* partS    = (float*)alloc((size_t)STATS_BLOCKS * FDIM * 4);
  float* partQ    = (float*)alloc((size_t)STATS_BLOCKS * FDIM * 4);
  int* deg        = (int*)alloc((size_t)N * 4);
  float* dinv     = (float*)alloc((size_t)N * 4);
  float* countsf  = (float*)alloc(NGRAPH * 4);
  float* aff_a    = (float*)alloc(FDIM * 4);
  float* aff_b    = (float*)alloc(FDIM * 4);
  __half* W16T    = (__half*)alloc((size_t)3 * FDIM * FDIM * 2);  // W0^T,W1^T,W2^T fp16
  __half* Hagg16  = (__half*)alloc((size_t)N * FDIM * 2);   // pre-squash h, [4][N][32]
  float2* S2SW    = (float2*)alloc((size_t)N * NSLICE * 8); // [slice][node] {pp,sw}
  float* wsP      = (float*)alloc((size_t)3 * finishBlocks * FDIM * 4);  // block partials
  float* msP      = (float*)alloc((size_t)3 * finishBlocks * FDIM * 4);
  unsigned* mxP   = (unsigned*)alloc((size_t)3 * finishBlocks * FDIM * 4);
  u16* ell16      = (u16*)alloc((size_t)N * ELLCAP * 2 + 1024);  // [N][64] u16
  int* histA      = (int*)alloc((size_t)nbH * nbkt * 4);
  int* histOff    = (int*)alloc((size_t)nbH * nbkt * 4);
  int* colsum     = (int*)alloc((size_t)nbkt * 4);
  int* bucket_base= (int*)alloc((size_t)(nbkt + 1) * 4);
  unsigned* bucketed = (unsigned*)alloc((size_t)E * 4);
  (void)ws_size; (void)n_in; (void)out_size;

  hipMemsetAsync(w + zoff, 0, zbytes, stream);

  const int nbN = (N + 255) / 256;
  const int total4 = N * FDIM / 4;
  const int gemmBlocks = (N + 63) / 64;
  const int nbW = (3 * FDIM * FDIM + 255) / 256;
  const int nodeChunks = (N + 127) / 128;  // 128 nodes per (chunk, p0-pair)
  const int gatherBlocks = nodeChunks * 8 + WARMB;
  const size_t pstride = (size_t)finishBlocks * FDIM;

  // stats + bounds + W^T + sentinel + edge bucket-histogram (no global atomics)
  k_bn<<<STATS_BLOCKS + nbN + nbW + 1 + nbH, 256, 0, stream>>>(
      x, partS, partQ, total4, batch, gstart, gend, gcn_w, W16T, H0, H1,
      esrc, edst, histA, E, nbN, nbW, N);
  k_scan<<<nbkt, 64, 0, stream>>>(histA, histOff, colsum, nbH, nbkt);
  k_aff<<<2, 256, 0, stream>>>(partS, partQ, gamma, beta, aff_a, aff_b,
                               gstart, gend, countsf, colsum, bucket_base, nbkt, N);
  k_scatter<<<nbH, 256, 0, stream>>>(esrc, edst, histOff, bucket_base, bucketed, E, nbkt);
  k_build<<<nbkt, 256, 0, stream>>>(bucketed, bucket_base, ell16, deg, dinv, N);
  // MFMA gemm0 (writes dinv-scaled H0)
  k_gemm0<<<gemmBlocks, 512, 0, stream>>>(x, aff_a, aff_b,
                                          (const _Float16*)W16T, (_Float16*)H0,
                                          dinv, N);

  // layer 0: gather from H0 (sliced, warmed), finish -> H1 via W1^T
  k_gather<<<gatherBlocks, 512, 0, stream>>>((const __half*)H0, Hagg16, S2SW,
                                             deg, ell16, gcn_b, w_att, dinv, N);
  k_finish<1><<<finishBlocks, 512, 0, stream>>>((const __half*)Hagg16, S2SW,
                                                (_Float16*)H1,
                                                (const _Float16*)(W16T + FDIM * FDIM),
                                                batch, dinv, wsum, msum, maxenc,
                                                wsP, msP, mxP, N);
  // layer 1: gather from H1, finish -> H0 via W2^T
  k_gather<<<gatherBlocks, 512, 0, stream>>>((const __half*)H1, Hagg16, S2SW,
                                             deg, ell16, gcn_b + FDIM, w_att + FDIM,
                                             dinv, N);
  k_finish<1><<<finishBlocks, 512, 0, stream>>>((const __half*)Hagg16, S2SW,
                                                (_Float16*)H0,
                                                (const _Float16*)(W16T + 2 * FDIM * FDIM),
                                                batch, dinv, wsum, msum,
                                                maxenc + (size_t)NGRAPH * FDIM,
                                                wsP + pstride, msP + pstride,
                                                mxP + pstride, N);
  // layer 2: gather from H0, finish (no epilogue)
  k_gather<<<gatherBlocks, 512, 0, stream>>>((const __half*)H0, Hagg16, S2SW,
                                             deg, ell16, gcn_b + 2 * FDIM,
                                             w_att + 2 * FDIM, dinv, N);
  k_finish<0><<<finishBlocks, 512, 0, stream>>>((const __half*)Hagg16, S2SW,
                                                nullptr, nullptr,
                                                batch, dinv, wsum, msum,
                                                maxenc + (size_t)2 * NGRAPH * FDIM,
                                                wsP + 2 * pstride, msP + 2 * pstride,
                                                mxP + 2 * pstride, N);
  k_head<<<NGRAPH, 128, 0, stream>>>(wsum, msum, maxenc, countsf,
                                     wsP, msP, mxP, finishBlocks, gstart, gend,
                                     l1w, l1b, l2w, l2b, out);
}

// Round 12
// 337.352 us; speedup vs baseline: 1.0420x; 1.0420x over previous
//
#include <hip/hip_runtime.h>
#include <hip/hip_fp16.h>

#define FDIM 128
#define NGRAPH 256
#define NCLS 10
#define STATS_BLOCKS 256
#define ELLCAP 64       // ushort slots per node (128B row); max degree ~35 << 64
#define SXPITCH 136     // LDS X row pitch in halfs: 272B -> aligned
#define NSLICE 4        // feature slices of 32 (64B/node-slice) for XCD-local gathers
#define WARMB 512       // L2-warm blocks prepended to k_gather (64 per XCD)
#define FIN_NODES 32    // nodes per block in k_finish (8 waves x 4 nodes)
#define EPB 4096        // edges per histogram/scatter block (256 thr x 16)

typedef __attribute__((ext_vector_type(8))) _Float16 half8;
typedef __attribute__((ext_vector_type(4))) float floatx4;
typedef unsigned long long ull;
typedef unsigned short u16;

__device__ __forceinline__ unsigned encf(float f) {
  unsigned b = __float_as_uint(f);
  return (b & 0x80000000u) ? ~b : (b | 0x80000000u);
}
__device__ __forceinline__ float decf(unsigned u) {
  if (u == 0u) return 0.f;  // empty segment -> 0 (matches isfinite->0)
  return (u & 0x80000000u) ? __uint_as_float(u & 0x7FFFFFFFu) : __uint_as_float(~u);
}

// Hs: [NSLICE][(N+1)][32] _Float16; row N = zero sentinel. Hagg16: [NSLICE][N][32].
// S2SW: [NSLICE][N] float2. W16T: [3][128][128] (W^T fp16).
// ell16: [N][64] u16 (16-bit idx, N<65536; sentinel N). Built ATOMIC-FREE via
// bucket counting-sort: bucket = dst>>8 (<=256 buckets), LDS-only atomics.

// ---------- k_bn: BN stats + batch bounds + W^T fp16 + sentinel + edge HISTOGRAM ----------
__global__ __launch_bounds__(256) void k_bn(const float* __restrict__ x,
                                            float* __restrict__ partS,
                                            float* __restrict__ partQ, int total4,
                                            const int* __restrict__ batch,
                                            int* __restrict__ gstart,
                                            int* __restrict__ gend,
                                            const float* __restrict__ gcn_w,
                                            __half* __restrict__ W16T,
                                            __half* __restrict__ H0z,
                                            __half* __restrict__ H1z,
                                            const int* __restrict__ src,
                                            const int* __restrict__ dst,
                                            int* __restrict__ histA, int E,
                                            int nbN, int nbW, int N) {
  int t = threadIdx.x;
  int nbkt = (N + 255) >> 8;
  if (blockIdx.x >= STATS_BLOCKS + nbN + nbW + 1) {
    // per-block bucket histogram of non-self edges (LDS atomics only)
    int blkH = blockIdx.x - (STATS_BLOCKS + nbN + nbW + 1);
    __shared__ int cnt[256];
    for (int i = t; i < nbkt; i += 256) cnt[i] = 0;
    __syncthreads();
    int e0 = blkH * EPB;
#pragma unroll
    for (int i = 0; i < 16; i++) {
      int e = e0 + i * 256 + t;
      if (e < E) {
        int s = src[e], d = dst[e];
        if (s != d) atomicAdd(&cnt[d >> 8], 1);
      }
    }
    __syncthreads();
    for (int i = t; i < nbkt; i += 256) histA[blkH * nbkt + i] = cnt[i];
    return;
  }
  if (blockIdx.x >= STATS_BLOCKS + nbN + nbW) {
    // zero sentinel row N of every slice of both Hs buffers
    if (t < 256) {
      int buf = t >> 7, rem = t & 127;
      int s = rem >> 5, f = rem & 31;
      __half* B = buf ? H1z : H0z;
      B[((size_t)s * (N + 1) + N) * 32 + f] = __float2half(0.f);
    }
    return;
  }
  if (blockIdx.x >= STATS_BLOCKS + nbN) {
    // WT[l][n][k] = W[l][k][n], fp16 — 3*128*128 elems
    int idx = (blockIdx.x - STATS_BLOCKS - nbN) * 256 + t;
    if (idx < 3 * FDIM * FDIM) {
      int l = idx >> 14;
      int rem = idx & 16383;
      int n = rem >> 7;
      int k = rem & 127;
      W16T[idx] = __float2half(gcn_w[l * FDIM * FDIM + k * FDIM + n]);
    }
    return;
  }
  if (blockIdx.x >= STATS_BLOCKS) {
    int e = (blockIdx.x - STATS_BLOCKS) * 256 + t;
    if (e < N) {
      int b = batch[e];
      if (e == 0 || batch[e - 1] != b) gstart[b] = e;
      if (e == N - 1) gend[b] = N;
      else if (batch[e + 1] != b) gend[b] = e + 1;
    }
    return;
  }
  __shared__ float ss[1024];
  __shared__ float sq[1024];
  float s0 = 0, s1 = 0, s2 = 0, s3 = 0, q0 = 0, q1 = 0, q2 = 0, q3 = 0;
  for (int i = blockIdx.x * 256 + t; i < total4; i += STATS_BLOCKS * 256) {
    float4 v = ((const float4*)x)[i];
    s0 += v.x; q0 += v.x * v.x;
    s1 += v.y; q1 += v.y * v.y;
    s2 += v.z; q2 += v.z * v.z;
    s3 += v.w; q3 += v.w * v.w;
  }
  int fb = (t & 31) * 4, slot = t >> 5;
  ss[slot * 128 + fb + 0] = s0; ss[slot * 128 + fb + 1] = s1;
  ss[slot * 128 + fb + 2] = s2; ss[slot * 128 + fb + 3] = s3;
  sq[slot * 128 + fb + 0] = q0; sq[slot * 128 + fb + 1] = q1;
  sq[slot * 128 + fb + 2] = q2; sq[slot * 128 + fb + 3] = q3;
  __syncthreads();
  if (t < 128) {
    float a = 0, b = 0;
    for (int s = 0; s < 8; s++) { a += ss[s * 128 + t]; b += sq[s * 128 + t]; }
    partS[blockIdx.x * 128 + t] = a;
    partQ[blockIdx.x * 128 + t] = b;
  }
}

// ---------- k_scan: per-bucket exclusive scan over blocks (one wave per bucket) ----------
__global__ __launch_bounds__(64) void k_scan(const int* __restrict__ histA,
                                             int* __restrict__ histOff,
                                             int* __restrict__ colsum,
                                             int nbH, int nbkt) {
  int bkt = blockIdx.x;
  int lane = threadIdx.x;
  int carry = 0;
  for (int c0 = 0; c0 < nbH; c0 += 64) {
    int blk = c0 + lane;
    int v = (blk < nbH) ? histA[blk * nbkt + bkt] : 0;
    int s = v;
#pragma unroll
    for (int m = 1; m < 64; m <<= 1) {
      int u = __shfl_up(s, m);
      if (lane >= m) s += u;
    }
    if (blk < nbH) histOff[blk * nbkt + bkt] = carry + s - v;
    carry += __shfl(s, 63);
  }
  if (lane == 0) colsum[bkt] = carry;
}

// ---------- k_aff: block 0 = BN affine + counts; block 1 = bucket_base scan ----------
__global__ __launch_bounds__(256) void k_aff(const float* __restrict__ partS,
                                             const float* __restrict__ partQ,
                                             const float* __restrict__ gamma,
                                             const float* __restrict__ beta,
                                             float* __restrict__ aff_a,
                                             float* __restrict__ aff_b,
                                             const int* __restrict__ gstart,
                                             const int* __restrict__ gend,
                                             float* __restrict__ countsf,
                                             const int* __restrict__ colsum,
                                             int* __restrict__ bucket_base,
                                             int nbkt, int N) {
  int t = threadIdx.x;
  if (blockIdx.x == 1) {
    __shared__ int sc[256];
    int orig = (t < nbkt) ? colsum[t] : 0;
    sc[t] = orig;
    __syncthreads();
    for (int m = 1; m < 256; m <<= 1) {
      int v = 0;
      if (t >= m) v = sc[t - m];
      __syncthreads();
      sc[t] += v;
      __syncthreads();
    }
    if (t < nbkt) bucket_base[t] = sc[t] - orig;   // exclusive
    if (t == 0) bucket_base[nbkt] = sc[255];       // total
    return;
  }
  if (t < NGRAPH) countsf[t] = fmaxf((float)(gend[t] - gstart[t]), 1.0f);
  if (t < FDIM) {
    float a = 0.f, b = 0.f;
    for (int bk = 0; bk < STATS_BLOCKS; bk++) {
      a += partS[bk * 128 + t];
      b += partQ[bk * 128 + t];
    }
    float invN = 1.0f / (float)N;
    float mu = a * invN;
    float var = b * invN - mu * mu;
    float inv = rsqrtf(var + 1e-5f);
    float ga = gamma[t] * inv;
    aff_a[t] = ga;
    aff_b[t] = beta[t] - mu * ga;
  }
}

// ---------- k_scatter: edges -> bucket-sorted packed array (LDS atomics only) ----------
__global__ __launch_bounds__(256) void k_scatter(const int* __restrict__ src,
                                                 const int* __restrict__ dst,
                                                 const int* __restrict__ histOff,
                                                 const int* __restrict__ bucket_base,
                                                 unsigned* __restrict__ bucketed,
                                                 int E, int nbkt) {
  __shared__ int off[256];
  int t = threadIdx.x;
  for (int i = t; i < nbkt; i += 256)
    off[i] = bucket_base[i] + histOff[blockIdx.x * nbkt + i];
  __syncthreads();
  int e0 = blockIdx.x * EPB;
#pragma unroll
  for (int i = 0; i < 16; i++) {
    int e = e0 + i * 256 + t;
    if (e < E) {
      int s = src[e], d = dst[e];
      if (s != d) {
        int pos = atomicAdd(&off[d >> 8], 1);
        bucketed[pos] = ((unsigned)(d & 255) << 16) | (unsigned)s;
      }
    }
  }
}

// ---------- k_build: one block per bucket -> ell16 rows + deg/dinv + sentinel pad ----------
__global__ __launch_bounds__(256) void k_build(const unsigned* __restrict__ bucketed,
                                               const int* __restrict__ bucket_base,
                                               u16* __restrict__ ell16,
                                               int* __restrict__ deg,
                                               float* __restrict__ dinv, int N) {
  __shared__ int cnt[256];
  int t = threadIdx.x;
  int b = blockIdx.x;
  cnt[t] = 0;
  __syncthreads();
  int e0 = bucket_base[b], e1 = bucket_base[b + 1];
  for (int e = e0 + t; e < e1; e += 256) {
    unsigned u = bucketed[e];
    int dlo = (int)(u >> 16);
    int s = (int)(u & 0xffffu);
    int slot = atomicAdd(&cnt[dlo], 1);
    if (slot < ELLCAP)
      ell16[(size_t)((b << 8) + dlo) * ELLCAP + slot] = (u16)s;
  }
  __syncthreads();
  int node = (b << 8) + t;
  if (node < N) {
    int d = min(cnt[t], ELLCAP);
    int pd = (d + 3) & ~3;                 // pad to 4 (one gather-iter granularity)
    deg[node] = pd;
    dinv[node] = rsqrtf(1.0f + (float)d);
    for (int j = d; j < pd; j++) ell16[(size_t)node * ELLCAP + j] = (u16)N;
  }
}

// ---------- gemm0 (MFMA): H0 = dinv * (affine(x) @ W0), sliced fp16 output ----------
__global__ __launch_bounds__(512) void k_gemm0(const float* __restrict__ x,
                                               const float* __restrict__ aff_a,
                                               const float* __restrict__ aff_b,
                                               const _Float16* __restrict__ WT,
                                               _Float16* __restrict__ Hout,
                                               const float* __restrict__ dinv,
                                               int N) {
  int t = threadIdx.x;
  __shared__ _Float16 sX[64 * SXPITCH];
  __shared__ float sDV[64];
  int nb = blockIdx.x * 64;
  if (t < 64) sDV[t] = dinv[min(nb + t, N - 1)];
#pragma unroll
  for (int i = 0; i < 4; i++) {
    int idx = i * 512 + t;          // 0..2047
    int row = idx >> 5;             // 0..63
    int c4 = idx & 31;              // float4 column
    int node = min(nb + row, N - 1);
    float4 v = *(const float4*)(x + (size_t)node * 128 + c4 * 4);
    float4 a = *(const float4*)(aff_a + c4 * 4);
    float4 b = *(const float4*)(aff_b + c4 * 4);
    __half2 h01 = __floats2half2_rn(fmaf(v.x, a.x, b.x), fmaf(v.y, a.y, b.y));
    __half2 h23 = __floats2half2_rn(fmaf(v.z, a.z, b.z), fmaf(v.w, a.w, b.w));
    uint2 st;
    st.x = *(unsigned*)&h01;
    st.y = *(unsigned*)&h23;
    *(uint2*)(sX + row * SXPITCH + c4 * 4) = st;
  }
  __syncthreads();
  int wv = t >> 6, l = t & 63;
  int r16 = l & 15, quad = l >> 4;
  int col = wv * 16 + r16;            // output feature
  int oslice = wv >> 1;
  int within = ((wv & 1) << 4) + r16; // col & 31
#pragma unroll
  for (int mt = 0; mt < 4; mt++) {
    floatx4 acc = (floatx4){0.f, 0.f, 0.f, 0.f};
#pragma unroll
    for (int ks = 0; ks < 4; ks++) {
      half8 bfrag = *(const half8*)(WT + (size_t)col * 128 + ks * 32 + quad * 8);
      half8 afrag = *(const half8*)(sX + (mt * 16 + r16) * SXPITCH + ks * 32 + quad * 8);
      acc = __builtin_amdgcn_mfma_f32_16x16x32_f16(afrag, bfrag, acc, 0, 0, 0);
    }
#pragma unroll
    for (int j = 0; j < 4; j++) {
      int row = mt * 16 + quad * 4 + j;
      int node = nb + row;
      if (node < N)
        Hout[((size_t)oslice * (N + 1) + node) * 32 + within] = (_Float16)(acc[j] * sDV[row]);
    }
  }
}

// ---------- pass A: XCD-local sliced aggregation, feature-major lanes, u16 idx ----------
// Warm blocks: stream this XCD's 3.2MB slice + its parity-half's idx rows (first 64B)
// into L2. Gather blocks: one wave per (4 nodes, slice); lanes = nd(4) x eg(2) x fl(8).
// One packed uint idx load (2 edges) + 2 gathers per lane per 4-edge iter.
__global__ __launch_bounds__(512) void k_gather(const __half* __restrict__ Hs,
                                                __half* __restrict__ Hagg16,
                                                float2* __restrict__ S2SW,
                                                const int* __restrict__ deg,
                                                const u16* __restrict__ ell16,
                                                const float* __restrict__ bias,
                                                const float* __restrict__ watt,
                                                const float* __restrict__ dinv,
                                                int N) {
  int bid = blockIdx.x;
  int t = threadIdx.x;
  int xcd = bid & 7;
  int slice = xcd >> 1;
  if (bid < WARMB) {
    int wb = bid >> 3;                     // 0..63 within this XCD
    const float4* p = (const float4*)(Hs + (size_t)slice * (N + 1) * 32);
    size_t total = (size_t)(N + 1) * 4;    // 16B units per slice
    float acc = 0.f;
    for (size_t i = (size_t)wb * 512 + t; i < total; i += (size_t)64 * 512) {
      float4 v = p[i];
      acc += (v.x + v.y) + (v.z + v.w);
    }
    // warm this XCD's parity-half idx rows (first 64B = 32 u16 slots per node)
    int p0 = xcd & 1;
    const unsigned* e32 = (const unsigned*)ell16;
    int chunks = (N + 63) / 64;            // each (chunk,p0) covers 32 nodes
    int node_off = t >> 4, word = t & 15;  // 32 nodes x 16 uints = 512 threads
    for (int c = wb; c < chunks; c += 64) {
      int node = (2 * c + p0) * 32 + node_off;
      if (node < N) acc += (float)(e32[(size_t)node * 32 + word] & 1u);
    }
    asm volatile("" :: "v"(acc));          // keep loads alive
    return;
  }
  int gb = bid - WARMB;                    // WARMB%8==0 so gb&7 == bid&7
  int p0 = xcd & 1;
  int chunk = gb >> 3;
  int wv = t >> 6, l = t & 63;
  int nodeBase = ((chunk * 2 + p0) * 8 + wv) * 4;   // 4 nodes per wave
  if (nodeBase >= N) return;
  int nd = l >> 4;                         // node within group
  int eg = (l >> 3) & 1;                   // edge parity (owns 2 consecutive slots)
  int fl = l & 7;                          // 8B chunk (4 features) within slice
  int node = min(nodeBase + nd, N - 1);
  bool nvalid = (nodeBase + nd) < N;
  const __half* HsS = Hs + (size_t)slice * (N + 1) * 32;
  int pd = deg[node];                      // padded multiple of 4
  float dn = dinv[node];
  int mx = pd;
  mx = max(mx, __shfl_xor(mx, 16));
  mx = max(mx, __shfl_xor(mx, 32));        // group max (all lanes agree)
  size_t ebase = (size_t)node * ELLCAP;    // u16 units; *2B = 128B-aligned row
  // self row (independent; issue early)
  uint2 sv = *(const uint2*)(HsS + (size_t)node * 32 + fl * 4);
  float a0 = 0.f, a1 = 0.f, a2 = 0.f, a3 = 0.f;
  for (int j = 0; j < mx; j += 4) {
    int i0 = j + 2 * eg, i1 = i0 + 1;
    unsigned u = *(const unsigned*)(ell16 + ebase + i0);  // 2 packed u16 idx
    int s0 = (int)(u & 0xffffu);
    int s1 = (int)(u >> 16);
    s0 = (i0 < pd) ? s0 : N;               // slots >= pd (other node longer) -> sentinel
    s1 = (i1 < pd) ? s1 : N;
    uint2 v0 = *(const uint2*)(HsS + (size_t)s0 * 32 + fl * 4);
    uint2 v1 = *(const uint2*)(HsS + (size_t)s1 * 32 + fl * 4);
    float2 f00 = __half22float2(*(__half2*)&v0.x);
    float2 f01 = __half22float2(*(__half2*)&v0.y);
    float2 f10 = __half22float2(*(__half2*)&v1.x);
    float2 f11 = __half22float2(*(__half2*)&v1.y);
    a0 += f00.x + f10.x;
    a1 += f00.y + f10.y;
    a2 += f01.x + f11.x;
    a3 += f01.y + f11.y;
  }
  // merge the two edge-parity halves (lanes l and l^8 hold same features)
  a0 += __shfl_xor(a0, 8);
  a1 += __shfl_xor(a1, 8);
  a2 += __shfl_xor(a2, 8);
  a3 += __shfl_xor(a3, 8);
  // add self once
  float2 s0f = __half22float2(*(__half2*)&sv.x);
  float2 s1f = __half22float2(*(__half2*)&sv.y);
  a0 += s0f.x; a1 += s0f.y; a2 += s1f.x; a3 += s1f.y;
  // h = dn*sum + bias for this lane's 4 features
  int gf = (slice << 5) + (fl << 2);
  float4 bb = *(const float4*)(bias + gf);
  float h0 = fmaf(dn, a0, bb.x);
  float h1 = fmaf(dn, a1, bb.y);
  float h2 = fmaf(dn, a2, bb.z);
  float h3 = fmaf(dn, a3, bb.w);
  float4 wa = *(const float4*)(watt + gf);
  float pp = h0 * h0 + h1 * h1 + h2 * h2 + h3 * h3;
  float sw = h0 * wa.x + h1 * wa.y + h2 * wa.z + h3 * wa.w;
  // reduce over the 8 fl lanes (xor 1,2,4 keep nd and eg fixed)
#pragma unroll
  for (int m = 1; m < 8; m <<= 1) {
    pp += __shfl_xor(pp, m);
    sw += __shfl_xor(sw, m);
  }
  if (nvalid && (l & 15) == 0)
    S2SW[(size_t)slice * N + node] = make_float2(pp, sw);   // cached store, L2 merges
  if (nvalid && eg == 0) {
    __half2 p01 = __floats2half2_rn(h0, h1);
    __half2 p23 = __floats2half2_rn(h2, h3);
    ull u = ((ull)*(unsigned*)&p23 << 32) | (ull)*(unsigned*)&p01;
    // [slice][node][32]: 8 fl lanes x 8B = full contiguous 64B line per node
    __builtin_nontemporal_store(u, (ull*)(Hagg16 + ((size_t)slice * N + node) * 32 + fl * 4));
  }
}

// ---------- pass B: squash + attention + partial pooling + MFMA epilogue ----------
template <int GEMM>
__global__ __launch_bounds__(512) void k_finish(const __half* __restrict__ Hagg16,
                                                const float2* __restrict__ S2SW,
                                                _Float16* __restrict__ HsNext,
                                                const _Float16* __restrict__ WT,
                                                const int* __restrict__ batch,
                                                const float* __restrict__ dinv,
                                                float* __restrict__ wsum,
                                                float* __restrict__ msum,
                                                unsigned* __restrict__ maxenc,
                                                float* __restrict__ wsP,
                                                float* __restrict__ msP,
                                                unsigned* __restrict__ mxP,
                                                int N) {
  __shared__ float l_ws[8][128];
  __shared__ float l_ms[8][128];
  __shared__ unsigned l_mx[8][128];
  __shared__ _Float16 sX[FIN_NODES * SXPITCH];
  int t = threadIdx.x;
  int wv = t >> 6, l = t & 63;
  int nb = blockIdx.x * FIN_NODES;
  int g0 = batch[nb];
  int fb = 2 * l;
  // lane's feature pair 2l,2l+1 lives in slice l>>4 at half2 index l&15
  size_t hoff = ((size_t)(l >> 4) * N) * 32 + (l & 15) * 2;
  float wsx = 0.f, wsy = 0.f, msx = 0.f, msy = 0.f;
  unsigned mxx = 0u, mxy = 0u;
#pragma unroll
  for (int i = 0; i < 4; i++) {
    int node = nb + wv * 4 + i;
    bool valid = node < N;
    float2 xv = make_float2(0.f, 0.f);
    float att = 0.f, dn = 0.f;
    bool own = false;
    int g = g0;
    if (valid) {
      float2 q0 = S2SW[node];
      float2 q1 = S2SW[(size_t)N + node];
      float2 q2 = S2SW[(size_t)2 * N + node];
      float2 q3 = S2SW[(size_t)3 * N + node];
      float pnorm = (q0.x + q1.x) + (q2.x + q3.x);
      float swv = (q0.y + q1.y) + (q2.y + q3.y);
      float factor = (pnorm / (1.0f + pnorm)) * rsqrtf(pnorm + 1e-8f);
      float2 h = __half22float2(*(const __half2*)(Hagg16 + hoff + (size_t)node * 32));
      xv = make_float2(h.x * factor, h.y * factor);
      att = factor * swv;
      dn = dinv[node];
      g = batch[node];
      own = (g == g0);
    }
    if (GEMM) {
      __half2 sxv = __floats2half2_rn(xv.x * dn, xv.y * dn);
      *(__half2*)(sX + (wv * 4 + i) * SXPITCH + fb) = sxv;
    }
    if (own) {
      wsx += att * xv.x; wsy += att * xv.y;
      msx += xv.x; msy += xv.y;
      unsigned ex = encf(xv.x), ey = encf(xv.y);
      mxx = mxx > ex ? mxx : ex;
      mxy = mxy > ey ? mxy : ey;
    } else if (valid) {  // rare: graph boundary inside block -> overflow atomics
      int basei = g * 128 + fb;
      atomicAdd(wsum + basei + 0, att * xv.x);
      atomicAdd(wsum + basei + 1, att * xv.y);
      atomicAdd(msum + basei + 0, xv.x);
      atomicAdd(msum + basei + 1, xv.y);
      atomicMax(maxenc + basei + 0, encf(xv.x));
      atomicMax(maxenc + basei + 1, encf(xv.y));
    }
  }
  l_ws[wv][fb] = wsx; l_ws[wv][fb + 1] = wsy;
  l_ms[wv][fb] = msx; l_ms[wv][fb + 1] = msy;
  l_mx[wv][fb] = mxx; l_mx[wv][fb + 1] = mxy;
  __syncthreads();
  if (t < 128) {
    float a = 0.f, b = 0.f;
    unsigned m = 0u;
#pragma unroll
    for (int w = 0; w < 8; w++) {
      a += l_ws[w][t];
      b += l_ms[w][t];
      unsigned v = l_mx[w][t];
      m = m > v ? m : v;
    }
    size_t pb = (size_t)blockIdx.x * 128 + t;
    wsP[pb] = a;
    msP[pb] = b;
    mxP[pb] = m;
  }
  if (GEMM) {
    int r16 = l & 15, quad = l >> 4;
    int col = wv * 16 + r16;            // global output feature
    int oslice = wv >> 1;
    int within = ((wv & 1) << 4) + r16; // col & 31
    floatx4 acc0 = (floatx4){0.f, 0.f, 0.f, 0.f};
    floatx4 acc1 = (floatx4){0.f, 0.f, 0.f, 0.f};
#pragma unroll
    for (int ks = 0; ks < 4; ks++) {
      half8 bfrag = *(const half8*)(WT + (size_t)col * 128 + ks * 32 + quad * 8);
      half8 af0 = *(const half8*)(sX + r16 * SXPITCH + ks * 32 + quad * 8);
      half8 af1 = *(const half8*)(sX + (16 + r16) * SXPITCH + ks * 32 + quad * 8);
      acc0 = __builtin_amdgcn_mfma_f32_16x16x32_f16(af0, bfrag, acc0, 0, 0, 0);
      acc1 = __builtin_amdgcn_mfma_f32_16x16x32_f16(af1, bfrag, acc1, 0, 0, 0);
    }
#pragma unroll
    for (int j = 0; j < 4; j++) {
      int row = quad * 4 + j;
      int n0 = nb + row;
      int n1 = nb + 16 + row;
      if (n0 < N) HsNext[((size_t)oslice * (N + 1) + n0) * 32 + within] = (_Float16)acc0[j];
      if (n1 < N) HsNext[((size_t)oslice * (N + 1) + n1) * 32 + within] = (_Float16)acc1[j];
    }
  }
}

// ---------- MLP head: per-graph reduction of block partials + log_softmax ----------
__global__ __launch_bounds__(128) void k_head(const float* __restrict__ wsum,
                                              const float* __restrict__ msum,
                                              const unsigned* __restrict__ maxenc,
                                              const float* __restrict__ countsf,
                                              const float* __restrict__ wsP,
                                              const float* __restrict__ msP,
                                              const unsigned* __restrict__ mxP,
                                              int NB,
                                              const int* __restrict__ gstart,
                                              const int* __restrict__ gend,
                                              const float* __restrict__ l1w,
                                              const float* __restrict__ l1b,
                                              const float* __restrict__ l2w,
                                              const float* __restrict__ l2b,
                                              float* __restrict__ out) {
  int g = blockIdx.x, t = threadIdx.x;
  __shared__ float rep[384];
  __shared__ float h1[128];
  __shared__ float lg[NCLS];
  int bs = (gstart[g] + FIN_NODES - 1) / FIN_NODES;
  int be = (gend[g] + FIN_NODES - 1) / FIN_NODES;  // blocks b with batch[32b]==g
  float ws = wsum[g * 128 + t];  // overflow contributions (all layers accumulated)
  float ms = msum[g * 128 + t];
  float r2 = 0.f;
  for (int lyr = 0; lyr < 3; lyr++) {
    unsigned mx = maxenc[(size_t)lyr * NGRAPH * 128 + g * 128 + t];
    const float* wp = wsP + (size_t)lyr * NB * 128;
    const float* mp = msP + (size_t)lyr * NB * 128;
    const unsigned* xp = mxP + (size_t)lyr * NB * 128;
    for (int b = bs; b < be; b++) {
      ws += wp[(size_t)b * 128 + t];
      ms += mp[(size_t)b * 128 + t];
      unsigned v = xp[(size_t)b * 128 + t];
      mx = mx > v ? mx : v;
    }
    r2 += decf(mx);
  }
  float invc = 1.0f / countsf[g];
  rep[t] = ws;
  rep[128 + t] = ms * invc;
  rep[256 + t] = r2;
  __syncthreads();
  float acc = l1b[t];
  for (int k = 0; k < 384; k++) acc = fmaf(rep[k], l1w[k * 128 + t], acc);
  h1[t] = fmaxf(acc, 0.f);
  __syncthreads();
  if (t < NCLS) {
    float a = l2b[t];
    for (int j = 0; j < 128; j++) a = fmaf(h1[j], l2w[j * NCLS + t], a);
    lg[t] = a;
  }
  __syncthreads();
  if (t < NCLS) {
    float m = lg[0];
    for (int c = 1; c < NCLS; c++) m = fmaxf(m, lg[c]);
    float s = 0.f;
    for (int c = 0; c < NCLS; c++) s += expf(lg[c] - m);
    out[g * NCLS + t] = lg[t] - m - logf(s);
  }
}

extern "C" void kernel_launch(void* const* d_in, const int* in_sizes, int n_in,
                              void* d_out, int out_size, void* d_ws, size_t ws_size,
                              hipStream_t stream) {
  const float* x      = (const float*)d_in[0];
  const int* edge     = (const int*)d_in[1];
  const int* batch    = (const int*)d_in[2];
  const float* gamma  = (const float*)d_in[3];
  const float* beta   = (const float*)d_in[4];
  const float* gcn_w  = (const float*)d_in[5];
  const float* gcn_b  = (const float*)d_in[6];
  const float* w_att  = (const float*)d_in[7];
  const float* l1w    = (const float*)d_in[8];
  const float* l1b    = (const float*)d_in[9];
  const float* l2w    = (const float*)d_in[10];
  const float* l2b    = (const float*)d_in[11];
  float* out          = (float*)d_out;

  const int N = in_sizes[0] / FDIM;   // 50000 (< 65536: u16 indices valid)
  const int E = in_sizes[1] / 2;      // 640000
  const int* esrc = edge;
  const int* edst = edge + E;

  char* w = (char*)d_ws;
  size_t off = 0;
  auto alloc = [&](size_t bytes) {
    void* p = (void*)(w + off);
    off += (bytes + 1023) & ~(size_t)1023;
    return p;
  };
  const int finishBlocks = (N + FIN_NODES - 1) / FIN_NODES;
  const int nbkt = (N + 255) >> 8;          // buckets (dst>>8), <=256
  const int nbH = (E + EPB - 1) / EPB;      // histogram/scatter blocks
  __half* H0 = (__half*)alloc((size_t)(N + 1) * FDIM * 2);  // sliced [4][(N+1)][32]
  __half* H1 = (__half*)alloc((size_t)(N + 1) * FDIM * 2);
  // zero zone start
  size_t zoff = off;
  int* gstart      = (int*)alloc(NGRAPH * 4);
  int* gend        = (int*)alloc(NGRAPH * 4);
  float* wsum      = (float*)alloc(NGRAPH * FDIM * 4);   // overflow-only
  float* msum      = (float*)alloc(NGRAPH * FDIM * 4);
  unsigned* maxenc = (unsigned*)alloc((size_t)3 * NGRAPH * FDIM * 4);
  size_t zbytes = off - zoff;
  // non-zeroed
  float* partS    = (float*)alloc((size_t)STATS_BLOCKS * FDIM * 4);
  float* partQ    = (float*)alloc((size_t)STATS_BLOCKS * FDIM * 4);
  int* deg        = (int*)alloc((size_t)N * 4);
  float* dinv     = (float*)alloc((size_t)N * 4);
  float* countsf  = (float*)alloc(NGRAPH * 4);
  float* aff_a    = (float*)alloc(FDIM * 4);
  float* aff_b    = (float*)alloc(FDIM * 4);
  __half* W16T    = (__half*)alloc((size_t)3 * FDIM * FDIM * 2);  // W0^T,W1^T,W2^T fp16
  __half* Hagg16  = (__half*)alloc((size_t)N * FDIM * 2);   // pre-squash h, [4][N][32]
  float2* S2SW    = (float2*)alloc((size_t)N * NSLICE * 8); // [slice][node] {pp,sw}
  float* wsP      = (float*)alloc((size_t)3 * finishBlocks * FDIM * 4);  // block partials
  float* msP      = (float*)alloc((size_t)3 * finishBlocks * FDIM * 4);
  unsigned* mxP   = (unsigned*)alloc((size_t)3 * finishBlocks * FDIM * 4);
  u16* ell16      = (u16*)alloc((size_t)N * ELLCAP * 2 + 1024);  // [N][64] u16
  int* histA      = (int*)alloc((size_t)nbH * nbkt * 4);
  int* histOff    = (int*)alloc((size_t)nbH * nbkt * 4);
  int* colsum     = (int*)alloc((size_t)nbkt * 4);
  int* bucket_base= (int*)alloc((size_t)(nbkt + 1) * 4);
  unsigned* bucketed = (unsigned*)alloc((size_t)E * 4);
  (void)ws_size; (void)n_in; (void)out_size;

  hipMemsetAsync(w + zoff, 0, zbytes, stream);

  const int nbN = (N + 255) / 256;
  const int total4 = N * FDIM / 4;
  const int gemmBlocks = (N + 63) / 64;
  const int nbW = (3 * FDIM * FDIM + 255) / 256;
  const int nodeChunks = (N + 63) / 64;   // 64 nodes per (chunk, p0-pair)
  const int gatherBlocks = nodeChunks * 8 + WARMB;
  const size_t pstride = (size_t)finishBlocks * FDIM;

  // stats + bounds + W^T + sentinel + edge bucket-histogram (no global atomics)
  k_bn<<<STATS_BLOCKS + nbN + nbW + 1 + nbH, 256, 0, stream>>>(
      x, partS, partQ, total4, batch, gstart, gend, gcn_w, W16T, H0, H1,
      esrc, edst, histA, E, nbN, nbW, N);
  k_scan<<<nbkt, 64, 0, stream>>>(histA, histOff, colsum, nbH, nbkt);
  k_aff<<<2, 256, 0, stream>>>(partS, partQ, gamma, beta, aff_a, aff_b,
                               gstart, gend, countsf, colsum, bucket_base, nbkt, N);
  k_scatter<<<nbH, 256, 0, stream>>>(esrc, edst, histOff, bucket_base, bucketed, E, nbkt);
  k_build<<<nbkt, 256, 0, stream>>>(bucketed, bucket_base, ell16, deg, dinv, N);
  // MFMA gemm0 (writes dinv-scaled H0)
  k_gemm0<<<gemmBlocks, 512, 0, stream>>>(x, aff_a, aff_b,
                                          (const _Float16*)W16T, (_Float16*)H0,
                                          dinv, N);

  // layer 0: gather from H0 (sliced, warmed), finish -> H1 via W1^T
  k_gather<<<gatherBlocks, 512, 0, stream>>>((const __half*)H0, Hagg16, S2SW,
                                             deg, ell16, gcn_b, w_att, dinv, N);
  k_finish<1><<<finishBlocks, 512, 0, stream>>>((const __half*)Hagg16, S2SW,
                                                (_Float16*)H1,
                                                (const _Float16*)(W16T + FDIM * FDIM),
                                                batch, dinv, wsum, msum, maxenc,
                                                wsP, msP, mxP, N);
  // layer 1: gather from H1, finish -> H0 via W2^T
  k_gather<<<gatherBlocks, 512, 0, stream>>>((const __half*)H1, Hagg16, S2SW,
                                             deg, ell16, gcn_b + FDIM, w_att + FDIM,
                                             dinv, N);
  k_finish<1><<<finishBlocks, 512, 0, stream>>>((const __half*)Hagg16, S2SW,
                                                (_Float16*)H0,
                                                (const _Float16*)(W16T + 2 * FDIM * FDIM),
                                                batch, dinv, wsum, msum,
                                                maxenc + (size_t)NGRAPH * FDIM,
                                                wsP + pstride, msP + pstride,
                                                mxP + pstride, N);
  // layer 2: gather from H0, finish (no epilogue)
  k_gather<<<gatherBlocks, 512, 0, stream>>>((const __half*)H0, Hagg16, S2SW,
                                             deg, ell16, gcn_b + 2 * FDIM,
                                             w_att + 2 * FDIM, dinv, N);
  k_finish<0><<<finishBlocks, 512, 0, stream>>>((const __half*)Hagg16, S2SW,
                                                nullptr, nullptr,
                                                batch, dinv, wsum, msum,
                                                maxenc + (size_t)2 * NGRAPH * FDIM,
                                                wsP + 2 * pstride, msP + 2 * pstride,
                                                mxP + 2 * pstride, N);
  k_head<<<NGRAPH, 128, 0, stream>>>(wsum, msum, maxenc, countsf,
                                     wsP, msP, mxP, finishBlocks, gstart, gend,
                                     l1w, l1b, l2w, l2b, out);
}

// Round 13
// 324.492 us; speedup vs baseline: 1.0833x; 1.0396x over previous
//
#include <hip/hip_runtime.h>
#include <hip/hip_fp16.h>

#define FDIM 128
#define NGRAPH 256
#define NCLS 10
#define STATS_BLOCKS 256
#define ELLCAP 64       // ushort slots per node (128B row); max degree ~35 << 64
#define SXPITCH 136     // LDS X row pitch in halfs: 272B -> aligned
#define NSLICE 4        // feature slices of 32 (64B/node-slice) for XCD-local gathers
#define WARMB 512       // L2-warm blocks prepended to k_gather (64 per XCD)
#define FIN_NODES 32    // nodes per block in k_finish (8 waves x 4 nodes)
#define EPB 4096        // edges per histogram/scatter block (256 thr x 16)

typedef __attribute__((ext_vector_type(8))) _Float16 half8;
typedef __attribute__((ext_vector_type(4))) float floatx4;
typedef unsigned long long ull;
typedef unsigned short u16;

__device__ __forceinline__ unsigned encf(float f) {
  unsigned b = __float_as_uint(f);
  return (b & 0x80000000u) ? ~b : (b | 0x80000000u);
}
__device__ __forceinline__ float decf(unsigned u) {
  if (u == 0u) return 0.f;  // empty segment -> 0 (matches isfinite->0)
  return (u & 0x80000000u) ? __uint_as_float(u & 0x7FFFFFFFu) : __uint_as_float(~u);
}

// Hs: [NSLICE][(N+1)][32] _Float16; row N = zero sentinel. Hagg16: [NSLICE][N][32].
// S2SW: [NSLICE][N] float2. W16T: [3][128][128] (W^T fp16).
// ell16: [N][64] u16 (16-bit idx, N<65536; sentinel N). Built ATOMIC-FREE via
// bucket counting-sort: bucket = dst>>8 (<=256 buckets), LDS-only atomics.

// ---------- k_bn: BN stats + batch bounds + W^T fp16 + sentinel + edge HISTOGRAM ----------
__global__ __launch_bounds__(256) void k_bn(const float* __restrict__ x,
                                            float* __restrict__ partS,
                                            float* __restrict__ partQ, int total4,
                                            const int* __restrict__ batch,
                                            int* __restrict__ gstart,
                                            int* __restrict__ gend,
                                            const float* __restrict__ gcn_w,
                                            __half* __restrict__ W16T,
                                            __half* __restrict__ H0z,
                                            __half* __restrict__ H1z,
                                            const int* __restrict__ src,
                                            const int* __restrict__ dst,
                                            int* __restrict__ histA, int E,
                                            int nbN, int nbW, int N) {
  int t = threadIdx.x;
  int nbkt = (N + 255) >> 8;
  if (blockIdx.x >= STATS_BLOCKS + nbN + nbW + 1) {
    // per-block bucket histogram of non-self edges (LDS atomics only)
    int blkH = blockIdx.x - (STATS_BLOCKS + nbN + nbW + 1);
    __shared__ int cnt[256];
    for (int i = t; i < nbkt; i += 256) cnt[i] = 0;
    __syncthreads();
    int e0 = blkH * EPB;
#pragma unroll
    for (int i = 0; i < 16; i++) {
      int e = e0 + i * 256 + t;
      if (e < E) {
        int s = src[e], d = dst[e];
        if (s != d) atomicAdd(&cnt[d >> 8], 1);
      }
    }
    __syncthreads();
    for (int i = t; i < nbkt; i += 256) histA[blkH * nbkt + i] = cnt[i];
    return;
  }
  if (blockIdx.x >= STATS_BLOCKS + nbN + nbW) {
    // zero sentinel row N of every slice of both Hs buffers
    if (t < 256) {
      int buf = t >> 7, rem = t & 127;
      int s = rem >> 5, f = rem & 31;
      __half* B = buf ? H1z : H0z;
      B[((size_t)s * (N + 1) + N) * 32 + f] = __float2half(0.f);
    }
    return;
  }
  if (blockIdx.x >= STATS_BLOCKS + nbN) {
    // WT[l][n][k] = W[l][k][n], fp16 — 3*128*128 elems
    int idx = (blockIdx.x - STATS_BLOCKS - nbN) * 256 + t;
    if (idx < 3 * FDIM * FDIM) {
      int l = idx >> 14;
      int rem = idx & 16383;
      int n = rem >> 7;
      int k = rem & 127;
      W16T[idx] = __float2half(gcn_w[l * FDIM * FDIM + k * FDIM + n]);
    }
    return;
  }
  if (blockIdx.x >= STATS_BLOCKS) {
    int e = (blockIdx.x - STATS_BLOCKS) * 256 + t;
    if (e < N) {
      int b = batch[e];
      if (e == 0 || batch[e - 1] != b) gstart[b] = e;
      if (e == N - 1) gend[b] = N;
      else if (batch[e + 1] != b) gend[b] = e + 1;
    }
    return;
  }
  __shared__ float ss[1024];
  __shared__ float sq[1024];
  float s0 = 0, s1 = 0, s2 = 0, s3 = 0, q0 = 0, q1 = 0, q2 = 0, q3 = 0;
  for (int i = blockIdx.x * 256 + t; i < total4; i += STATS_BLOCKS * 256) {
    float4 v = ((const float4*)x)[i];
    s0 += v.x; q0 += v.x * v.x;
    s1 += v.y; q1 += v.y * v.y;
    s2 += v.z; q2 += v.z * v.z;
    s3 += v.w; q3 += v.w * v.w;
  }
  int fb = (t & 31) * 4, slot = t >> 5;
  ss[slot * 128 + fb + 0] = s0; ss[slot * 128 + fb + 1] = s1;
  ss[slot * 128 + fb + 2] = s2; ss[slot * 128 + fb + 3] = s3;
  sq[slot * 128 + fb + 0] = q0; sq[slot * 128 + fb + 1] = q1;
  sq[slot * 128 + fb + 2] = q2; sq[slot * 128 + fb + 3] = q3;
  __syncthreads();
  if (t < 128) {
    float a = 0, b = 0;
    for (int s = 0; s < 8; s++) { a += ss[s * 128 + t]; b += sq[s * 128 + t]; }
    partS[blockIdx.x * 128 + t] = a;
    partQ[blockIdx.x * 128 + t] = b;
  }
}

// ---------- k_scan: per-bucket exclusive scan over blocks (one wave per bucket) ----------
__global__ __launch_bounds__(64) void k_scan(const int* __restrict__ histA,
                                             int* __restrict__ histOff,
                                             int* __restrict__ colsum,
                                             int nbH, int nbkt) {
  int bkt = blockIdx.x;
  int lane = threadIdx.x;
  int carry = 0;
  for (int c0 = 0; c0 < nbH; c0 += 64) {
    int blk = c0 + lane;
    int v = (blk < nbH) ? histA[blk * nbkt + bkt] : 0;
    int s = v;
#pragma unroll
    for (int m = 1; m < 64; m <<= 1) {
      int u = __shfl_up(s, m);
      if (lane >= m) s += u;
    }
    if (blk < nbH) histOff[blk * nbkt + bkt] = carry + s - v;
    carry += __shfl(s, 63);
  }
  if (lane == 0) colsum[bkt] = carry;
}

// ---------- k_aff: block 0 = BN affine + counts; block 1 = bucket_base scan ----------
__global__ __launch_bounds__(256) void k_aff(const float* __restrict__ partS,
                                             const float* __restrict__ partQ,
                                             const float* __restrict__ gamma,
                                             const float* __restrict__ beta,
                                             float* __restrict__ aff_a,
                                             float* __restrict__ aff_b,
                                             const int* __restrict__ gstart,
                                             const int* __restrict__ gend,
                                             float* __restrict__ countsf,
                                             const int* __restrict__ colsum,
                                             int* __restrict__ bucket_base,
                                             int nbkt, int N) {
  int t = threadIdx.x;
  if (blockIdx.x == 1) {
    __shared__ int sc[256];
    int orig = (t < nbkt) ? colsum[t] : 0;
    sc[t] = orig;
    __syncthreads();
    for (int m = 1; m < 256; m <<= 1) {
      int v = 0;
      if (t >= m) v = sc[t - m];
      __syncthreads();
      sc[t] += v;
      __syncthreads();
    }
    if (t < nbkt) bucket_base[t] = sc[t] - orig;   // exclusive
    if (t == 0) bucket_base[nbkt] = sc[255];       // total
    return;
  }
  if (t < NGRAPH) countsf[t] = fmaxf((float)(gend[t] - gstart[t]), 1.0f);
  if (t < FDIM) {
    float a = 0.f, b = 0.f;
    for (int bk = 0; bk < STATS_BLOCKS; bk++) {
      a += partS[bk * 128 + t];
      b += partQ[bk * 128 + t];
    }
    float invN = 1.0f / (float)N;
    float mu = a * invN;
    float var = b * invN - mu * mu;
    float inv = rsqrtf(var + 1e-5f);
    float ga = gamma[t] * inv;
    aff_a[t] = ga;
    aff_b[t] = beta[t] - mu * ga;
  }
}

// ---------- k_scatter: edges -> bucket-sorted packed array (LDS atomics only) ----------
__global__ __launch_bounds__(256) void k_scatter(const int* __restrict__ src,
                                                 const int* __restrict__ dst,
                                                 const int* __restrict__ histOff,
                                                 const int* __restrict__ bucket_base,
                                                 unsigned* __restrict__ bucketed,
                                                 int E, int nbkt) {
  __shared__ int off[256];
  int t = threadIdx.x;
  for (int i = t; i < nbkt; i += 256)
    off[i] = bucket_base[i] + histOff[blockIdx.x * nbkt + i];
  __syncthreads();
  int e0 = blockIdx.x * EPB;
#pragma unroll
  for (int i = 0; i < 16; i++) {
    int e = e0 + i * 256 + t;
    if (e < E) {
      int s = src[e], d = dst[e];
      if (s != d) {
        int pos = atomicAdd(&off[d >> 8], 1);
        bucketed[pos] = ((unsigned)(d & 255) << 16) | (unsigned)s;
      }
    }
  }
}

// ---------- k_build: one block per bucket -> ell16 rows + deg/dinv + sentinel pad ----------
__global__ __launch_bounds__(256) void k_build(const unsigned* __restrict__ bucketed,
                                               const int* __restrict__ bucket_base,
                                               u16* __restrict__ ell16,
                                               int* __restrict__ deg,
                                               float* __restrict__ dinv, int N) {
  __shared__ int cnt[256];
  int t = threadIdx.x;
  int b = blockIdx.x;
  cnt[t] = 0;
  __syncthreads();
  int e0 = bucket_base[b], e1 = bucket_base[b + 1];
  for (int e = e0 + t; e < e1; e += 256) {
    unsigned u = bucketed[e];
    int dlo = (int)(u >> 16);
    int s = (int)(u & 0xffffu);
    int slot = atomicAdd(&cnt[dlo], 1);
    if (slot < ELLCAP)
      ell16[(size_t)((b << 8) + dlo) * ELLCAP + slot] = (u16)s;
  }
  __syncthreads();
  int node = (b << 8) + t;
  if (node < N) {
    int d = min(cnt[t], ELLCAP);
    int pd = (d + 3) & ~3;                 // pad to 4 (one gather-iter granularity)
    deg[node] = pd;
    dinv[node] = rsqrtf(1.0f + (float)d);
    for (int j = d; j < pd; j++) ell16[(size_t)node * ELLCAP + j] = (u16)N;
  }
}

// ---------- gemm0 (MFMA): H0 = dinv * (affine(x) @ W0), sliced fp16 output ----------
__global__ __launch_bounds__(512) void k_gemm0(const float* __restrict__ x,
                                               const float* __restrict__ aff_a,
                                               const float* __restrict__ aff_b,
                                               const _Float16* __restrict__ WT,
                                               _Float16* __restrict__ Hout,
                                               const float* __restrict__ dinv,
                                               int N) {
  int t = threadIdx.x;
  __shared__ _Float16 sX[64 * SXPITCH];
  __shared__ float sDV[64];
  int nb = blockIdx.x * 64;
  if (t < 64) sDV[t] = dinv[min(nb + t, N - 1)];
#pragma unroll
  for (int i = 0; i < 4; i++) {
    int idx = i * 512 + t;          // 0..2047
    int row = idx >> 5;             // 0..63
    int c4 = idx & 31;              // float4 column
    int node = min(nb + row, N - 1);
    float4 v = *(const float4*)(x + (size_t)node * 128 + c4 * 4);
    float4 a = *(const float4*)(aff_a + c4 * 4);
    float4 b = *(const float4*)(aff_b + c4 * 4);
    __half2 h01 = __floats2half2_rn(fmaf(v.x, a.x, b.x), fmaf(v.y, a.y, b.y));
    __half2 h23 = __floats2half2_rn(fmaf(v.z, a.z, b.z), fmaf(v.w, a.w, b.w));
    uint2 st;
    st.x = *(unsigned*)&h01;
    st.y = *(unsigned*)&h23;
    *(uint2*)(sX + row * SXPITCH + c4 * 4) = st;
  }
  __syncthreads();
  int wv = t >> 6, l = t & 63;
  int r16 = l & 15, quad = l >> 4;
  int col = wv * 16 + r16;            // output feature
  int oslice = wv >> 1;
  int within = ((wv & 1) << 4) + r16; // col & 31
#pragma unroll
  for (int mt = 0; mt < 4; mt++) {
    floatx4 acc = (floatx4){0.f, 0.f, 0.f, 0.f};
#pragma unroll
    for (int ks = 0; ks < 4; ks++) {
      half8 bfrag = *(const half8*)(WT + (size_t)col * 128 + ks * 32 + quad * 8);
      half8 afrag = *(const half8*)(sX + (mt * 16 + r16) * SXPITCH + ks * 32 + quad * 8);
      acc = __builtin_amdgcn_mfma_f32_16x16x32_f16(afrag, bfrag, acc, 0, 0, 0);
    }
#pragma unroll
    for (int j = 0; j < 4; j++) {
      int row = mt * 16 + quad * 4 + j;
      int node = nb + row;
      if (node < N)
        Hout[((size_t)oslice * (N + 1) + node) * 32 + within] = (_Float16)(acc[j] * sDV[row]);
    }
  }
}

// ---------- pass A: XCD-local sliced aggregation, feature-major lanes, u16 idx ----------
// Warm blocks: stream this XCD's 3.2MB slice + its parity-half's idx rows (first 64B)
// into L2. Gather blocks: one wave per (4 nodes, slice); lanes = nd(4) x eg(2) x fl(8).
// Edge loop unroll-2: 2 idx loads + 4 gathers in flight per lane (ILP probe).
__global__ __launch_bounds__(512) void k_gather(const __half* __restrict__ Hs,
                                                __half* __restrict__ Hagg16,
                                                float2* __restrict__ S2SW,
                                                const int* __restrict__ deg,
                                                const u16* __restrict__ ell16,
                                                const float* __restrict__ bias,
                                                const float* __restrict__ watt,
                                                const float* __restrict__ dinv,
                                                int N) {
  int bid = blockIdx.x;
  int t = threadIdx.x;
  int xcd = bid & 7;
  int slice = xcd >> 1;
  if (bid < WARMB) {
    int wb = bid >> 3;                     // 0..63 within this XCD
    const float4* p = (const float4*)(Hs + (size_t)slice * (N + 1) * 32);
    size_t total = (size_t)(N + 1) * 4;    // 16B units per slice
    float acc = 0.f;
    for (size_t i = (size_t)wb * 512 + t; i < total; i += (size_t)64 * 512) {
      float4 v = p[i];
      acc += (v.x + v.y) + (v.z + v.w);
    }
    // warm this XCD's parity-half idx rows (first 64B = 32 u16 slots per node)
    int p0 = xcd & 1;
    const unsigned* e32 = (const unsigned*)ell16;
    int chunks = (N + 63) / 64;            // each (chunk,p0) covers 32 nodes
    int node_off = t >> 4, word = t & 15;  // 32 nodes x 16 uints = 512 threads
    for (int c = wb; c < chunks; c += 64) {
      int node = (2 * c + p0) * 32 + node_off;
      if (node < N) acc += (float)(e32[(size_t)node * 32 + word] & 1u);
    }
    asm volatile("" :: "v"(acc));          // keep loads alive
    return;
  }
  int gb = bid - WARMB;                    // WARMB%8==0 so gb&7 == bid&7
  int p0 = xcd & 1;
  int chunk = gb >> 3;
  int wv = t >> 6, l = t & 63;
  int nodeBase = ((chunk * 2 + p0) * 8 + wv) * 4;   // 4 nodes per wave
  if (nodeBase >= N) return;
  int nd = l >> 4;                         // node within group
  int eg = (l >> 3) & 1;                   // edge parity (owns 2 consecutive slots)
  int fl = l & 7;                          // 8B chunk (4 features) within slice
  int node = min(nodeBase + nd, N - 1);
  bool nvalid = (nodeBase + nd) < N;
  const __half* HsS = Hs + (size_t)slice * (N + 1) * 32;
  int pd = deg[node];                      // padded multiple of 4
  float dn = dinv[node];
  int mx = pd;
  mx = max(mx, __shfl_xor(mx, 16));
  mx = max(mx, __shfl_xor(mx, 32));        // group max (all lanes agree)
  size_t ebase = (size_t)node * ELLCAP;    // u16 units; *2B = 128B-aligned row
  // self row (independent; issue early)
  uint2 sv = *(const uint2*)(HsS + (size_t)node * 32 + fl * 4);
  float a0 = 0.f, a1 = 0.f, a2 = 0.f, a3 = 0.f;
#pragma unroll 2
  for (int j = 0; j < mx; j += 4) {
    int i0 = j + 2 * eg, i1 = i0 + 1;
    unsigned u = *(const unsigned*)(ell16 + ebase + i0);  // 2 packed u16 idx
    int s0 = (int)(u & 0xffffu);
    int s1 = (int)(u >> 16);
    s0 = (i0 < pd) ? s0 : N;               // slots >= pd (other node longer) -> sentinel
    s1 = (i1 < pd) ? s1 : N;
    uint2 v0 = *(const uint2*)(HsS + (size_t)s0 * 32 + fl * 4);
    uint2 v1 = *(const uint2*)(HsS + (size_t)s1 * 32 + fl * 4);
    float2 f00 = __half22float2(*(__half2*)&v0.x);
    float2 f01 = __half22float2(*(__half2*)&v0.y);
    float2 f10 = __half22float2(*(__half2*)&v1.x);
    float2 f11 = __half22float2(*(__half2*)&v1.y);
    a0 += f00.x + f10.x;
    a1 += f00.y + f10.y;
    a2 += f01.x + f11.x;
    a3 += f01.y + f11.y;
  }
  // merge the two edge-parity halves (lanes l and l^8 hold same features)
  a0 += __shfl_xor(a0, 8);
  a1 += __shfl_xor(a1, 8);
  a2 += __shfl_xor(a2, 8);
  a3 += __shfl_xor(a3, 8);
  // add self once
  float2 s0f = __half22float2(*(__half2*)&sv.x);
  float2 s1f = __half22float2(*(__half2*)&sv.y);
  a0 += s0f.x; a1 += s0f.y; a2 += s1f.x; a3 += s1f.y;
  // h = dn*sum + bias for this lane's 4 features
  int gf = (slice << 5) + (fl << 2);
  float4 bb = *(const float4*)(bias + gf);
  float h0 = fmaf(dn, a0, bb.x);
  float h1 = fmaf(dn, a1, bb.y);
  float h2 = fmaf(dn, a2, bb.z);
  float h3 = fmaf(dn, a3, bb.w);
  float4 wa = *(const float4*)(watt + gf);
  float pp = h0 * h0 + h1 * h1 + h2 * h2 + h3 * h3;
  float sw = h0 * wa.x + h1 * wa.y + h2 * wa.z + h3 * wa.w;
  // reduce over the 8 fl lanes (xor 1,2,4 keep nd and eg fixed)
#pragma unroll
  for (int m = 1; m < 8; m <<= 1) {
    pp += __shfl_xor(pp, m);
    sw += __shfl_xor(sw, m);
  }
  if (nvalid && (l & 15) == 0)
    S2SW[(size_t)slice * N + node] = make_float2(pp, sw);   // cached store, L2 merges
  if (nvalid && eg == 0) {
    __half2 p01 = __floats2half2_rn(h0, h1);
    __half2 p23 = __floats2half2_rn(h2, h3);
    ull u = ((ull)*(unsigned*)&p23 << 32) | (ull)*(unsigned*)&p01;
    // [slice][node][32]: 8 fl lanes x 8B = full contiguous 64B line per node
    __builtin_nontemporal_store(u, (ull*)(Hagg16 + ((size_t)slice * N + node) * 32 + fl * 4));
  }
}

// ---------- pass B: squash + attention + partial pooling + MFMA epilogue ----------
template <int GEMM>
__global__ __launch_bounds__(512) void k_finish(const __half* __restrict__ Hagg16,
                                                const float2* __restrict__ S2SW,
                                                _Float16* __restrict__ HsNext,
                                                const _Float16* __restrict__ WT,
                                                const int* __restrict__ batch,
                                                const float* __restrict__ dinv,
                                                float* __restrict__ wsum,
                                                float* __restrict__ msum,
                                                unsigned* __restrict__ maxenc,
                                                float* __restrict__ wsP,
                                                float* __restrict__ msP,
                                                unsigned* __restrict__ mxP,
                                                int N) {
  __shared__ float l_ws[8][128];
  __shared__ float l_ms[8][128];
  __shared__ unsigned l_mx[8][128];
  __shared__ _Float16 sX[FIN_NODES * SXPITCH];
  int t = threadIdx.x;
  int wv = t >> 6, l = t & 63;
  int nb = blockIdx.x * FIN_NODES;
  int g0 = batch[nb];
  int fb = 2 * l;
  // lane's feature pair 2l,2l+1 lives in slice l>>4 at half2 index l&15
  size_t hoff = ((size_t)(l >> 4) * N) * 32 + (l & 15) * 2;
  float wsx = 0.f, wsy = 0.f, msx = 0.f, msy = 0.f;
  unsigned mxx = 0u, mxy = 0u;
#pragma unroll
  for (int i = 0; i < 4; i++) {
    int node = nb + wv * 4 + i;
    bool valid = node < N;
    float2 xv = make_float2(0.f, 0.f);
    float att = 0.f, dn = 0.f;
    bool own = false;
    int g = g0;
    if (valid) {
      float2 q0 = S2SW[node];
      float2 q1 = S2SW[(size_t)N + node];
      float2 q2 = S2SW[(size_t)2 * N + node];
      float2 q3 = S2SW[(size_t)3 * N + node];
      float pnorm = (q0.x + q1.x) + (q2.x + q3.x);
      float swv = (q0.y + q1.y) + (q2.y + q3.y);
      float factor = (pnorm / (1.0f + pnorm)) * rsqrtf(pnorm + 1e-8f);
      float2 h = __half22float2(*(const __half2*)(Hagg16 + hoff + (size_t)node * 32));
      xv = make_float2(h.x * factor, h.y * factor);
      att = factor * swv;
      dn = dinv[node];
      g = batch[node];
      own = (g == g0);
    }
    if (GEMM) {
      __half2 sxv = __floats2half2_rn(xv.x * dn, xv.y * dn);
      *(__half2*)(sX + (wv * 4 + i) * SXPITCH + fb) = sxv;
    }
    if (own) {
      wsx += att * xv.x; wsy += att * xv.y;
      msx += xv.x; msy += xv.y;
      unsigned ex = encf(xv.x), ey = encf(xv.y);
      mxx = mxx > ex ? mxx : ex;
      mxy = mxy > ey ? mxy : ey;
    } else if (valid) {  // rare: graph boundary inside block -> overflow atomics
      int basei = g * 128 + fb;
      atomicAdd(wsum + basei + 0, att * xv.x);
      atomicAdd(wsum + basei + 1, att * xv.y);
      atomicAdd(msum + basei + 0, xv.x);
      atomicAdd(msum + basei + 1, xv.y);
      atomicMax(maxenc + basei + 0, encf(xv.x));
      atomicMax(maxenc + basei + 1, encf(xv.y));
    }
  }
  l_ws[wv][fb] = wsx; l_ws[wv][fb + 1] = wsy;
  l_ms[wv][fb] = msx; l_ms[wv][fb + 1] = msy;
  l_mx[wv][fb] = mxx; l_mx[wv][fb + 1] = mxy;
  __syncthreads();
  if (t < 128) {
    float a = 0.f, b = 0.f;
    unsigned m = 0u;
#pragma unroll
    for (int w = 0; w < 8; w++) {
      a += l_ws[w][t];
      b += l_ms[w][t];
      unsigned v = l_mx[w][t];
      m = m > v ? m : v;
    }
    size_t pb = (size_t)blockIdx.x * 128 + t;
    wsP[pb] = a;
    msP[pb] = b;
    mxP[pb] = m;
  }
  if (GEMM) {
    int r16 = l & 15, quad = l >> 4;
    int col = wv * 16 + r16;            // global output feature
    int oslice = wv >> 1;
    int within = ((wv & 1) << 4) + r16; // col & 31
    floatx4 acc0 = (floatx4){0.f, 0.f, 0.f, 0.f};
    floatx4 acc1 = (floatx4){0.f, 0.f, 0.f, 0.f};
#pragma unroll
    for (int ks = 0; ks < 4; ks++) {
      half8 bfrag = *(const half8*)(WT + (size_t)col * 128 + ks * 32 + quad * 8);
      half8 af0 = *(const half8*)(sX + r16 * SXPITCH + ks * 32 + quad * 8);
      half8 af1 = *(const half8*)(sX + (16 + r16) * SXPITCH + ks * 32 + quad * 8);
      acc0 = __builtin_amdgcn_mfma_f32_16x16x32_f16(af0, bfrag, acc0, 0, 0, 0);
      acc1 = __builtin_amdgcn_mfma_f32_16x16x32_f16(af1, bfrag, acc1, 0, 0, 0);
    }
#pragma unroll
    for (int j = 0; j < 4; j++) {
      int row = quad * 4 + j;
      int n0 = nb + row;
      int n1 = nb + 16 + row;
      if (n0 < N) HsNext[((size_t)oslice * (N + 1) + n0) * 32 + within] = (_Float16)acc0[j];
      if (n1 < N) HsNext[((size_t)oslice * (N + 1) + n1) * 32 + within] = (_Float16)acc1[j];
    }
  }
}

// ---------- MLP head: per-graph reduction of block partials + log_softmax ----------
__global__ __launch_bounds__(128) void k_head(const float* __restrict__ wsum,
                                              const float* __restrict__ msum,
                                              const unsigned* __restrict__ maxenc,
                                              const float* __restrict__ countsf,
                                              const float* __restrict__ wsP,
                                              const float* __restrict__ msP,
                                              const unsigned* __restrict__ mxP,
                                              int NB,
                                              const int* __restrict__ gstart,
                                              const int* __restrict__ gend,
                                              const float* __restrict__ l1w,
                                              const float* __restrict__ l1b,
                                              const float* __restrict__ l2w,
                                              const float* __restrict__ l2b,
                                              float* __restrict__ out) {
  int g = blockIdx.x, t = threadIdx.x;
  __shared__ float rep[384];
  __shared__ float h1[128];
  __shared__ float lg[NCLS];
  int bs = (gstart[g] + FIN_NODES - 1) / FIN_NODES;
  int be = (gend[g] + FIN_NODES - 1) / FIN_NODES;  // blocks b with batch[32b]==g
  float ws = wsum[g * 128 + t];  // overflow contributions (all layers accumulated)
  float ms = msum[g * 128 + t];
  float r2 = 0.f;
  for (int lyr = 0; lyr < 3; lyr++) {
    unsigned mx = maxenc[(size_t)lyr * NGRAPH * 128 + g * 128 + t];
    const float* wp = wsP + (size_t)lyr * NB * 128;
    const float* mp = msP + (size_t)lyr * NB * 128;
    const unsigned* xp = mxP + (size_t)lyr * NB * 128;
    for (int b = bs; b < be; b++) {
      ws += wp[(size_t)b * 128 + t];
      ms += mp[(size_t)b * 128 + t];
      unsigned v = xp[(size_t)b * 128 + t];
      mx = mx > v ? mx : v;
    }
    r2 += decf(mx);
  }
  float invc = 1.0f / countsf[g];
  rep[t] = ws;
  rep[128 + t] = ms * invc;
  rep[256 + t] = r2;
  __syncthreads();
  float acc = l1b[t];
  for (int k = 0; k < 384; k++) acc = fmaf(rep[k], l1w[k * 128 + t], acc);
  h1[t] = fmaxf(acc, 0.f);
  __syncthreads();
  if (t < NCLS) {
    float a = l2b[t];
    for (int j = 0; j < 128; j++) a = fmaf(h1[j], l2w[j * NCLS + t], a);
    lg[t] = a;
  }
  __syncthreads();
  if (t < NCLS) {
    float m = lg[0];
    for (int c = 1; c < NCLS; c++) m = fmaxf(m, lg[c]);
    float s = 0.f;
    for (int c = 0; c < NCLS; c++) s += expf(lg[c] - m);
    out[g * NCLS + t] = lg[t] - m - logf(s);
  }
}

extern "C" void kernel_launch(void* const* d_in, const int* in_sizes, int n_in,
                              void* d_out, int out_size, void* d_ws, size_t ws_size,
                              hipStream_t stream) {
  const float* x      = (const float*)d_in[0];
  const int* edge     = (const int*)d_in[1];
  const int* batch    = (const int*)d_in[2];
  const float* gamma  = (const float*)d_in[3];
  const float* beta   = (const float*)d_in[4];
  const float* gcn_w  = (const float*)d_in[5];
  const float* gcn_b  = (const float*)d_in[6];
  const float* w_att  = (const float*)d_in[7];
  const float* l1w    = (const float*)d_in[8];
  const float* l1b    = (const float*)d_in[9];
  const float* l2w    = (const float*)d_in[10];
  const float* l2b    = (const float*)d_in[11];
  float* out          = (float*)d_out;

  const int N = in_sizes[0] / FDIM;   // 50000 (< 65536: u16 indices valid)
  const int E = in_sizes[1] / 2;      // 640000
  const int* esrc = edge;
  const int* edst = edge + E;

  char* w = (char*)d_ws;
  size_t off = 0;
  auto alloc = [&](size_t bytes) {
    void* p = (void*)(w + off);
    off += (bytes + 1023) & ~(size_t)1023;
    return p;
  };
  const int finishBlocks = (N + FIN_NODES - 1) / FIN_NODES;
  const int nbkt = (N + 255) >> 8;          // buckets (dst>>8), <=256
  const int nbH = (E + EPB - 1) / EPB;      // histogram/scatter blocks
  __half* H0 = (__half*)alloc((size_t)(N + 1) * FDIM * 2);  // sliced [4][(N+1)][32]
  __half* H1 = (__half*)alloc((size_t)(N + 1) * FDIM * 2);
  // zero zone start
  size_t zoff = off;
  int* gstart      = (int*)alloc(NGRAPH * 4);
  int* gend        = (int*)alloc(NGRAPH * 4);
  float* wsum      = (float*)alloc(NGRAPH * FDIM * 4);   // overflow-only
  float* msum      = (float*)alloc(NGRAPH * FDIM * 4);
  unsigned* maxenc = (unsigned*)alloc((size_t)3 * NGRAPH * FDIM * 4);
  size_t zbytes = off - zoff;
  // non-zeroed
  float* partS    = (float*)alloc((size_t)STATS_BLOCKS * FDIM * 4);
  float* partQ    = (float*)alloc((size_t)STATS_BLOCKS * FDIM * 4);
  int* deg        = (int*)alloc((size_t)N * 4);
  float* dinv     = (float*)alloc((size_t)N * 4);
  float* countsf  = (float*)alloc(NGRAPH * 4);
  float* aff_a    = (float*)alloc(FDIM * 4);
  float* aff_b    = (float*)alloc(FDIM * 4);
  __half* W16T    = (__half*)alloc((size_t)3 * FDIM * FDIM * 2);  // W0^T,W1^T,W2^T fp16
  __half* Hagg16  = (__half*)alloc((size_t)N * FDIM * 2);   // pre-squash h, [4][N][32]
  float2* S2SW    = (float2*)alloc((size_t)N * NSLICE * 8); // [slice][node] {pp,sw}
  float* wsP      = (float*)alloc((size_t)3 * finishBlocks * FDIM * 4);  // block partials
  float* msP      = (float*)alloc((size_t)3 * finishBlocks * FDIM * 4);
  unsigned* mxP   = (unsigned*)alloc((size_t)3 * finishBlocks * FDIM * 4);
  u16* ell16      = (u16*)alloc((size_t)N * ELLCAP * 2 + 1024);  // [N][64] u16
  int* histA      = (int*)alloc((size_t)nbH * nbkt * 4);
  int* histOff    = (int*)alloc((size_t)nbH * nbkt * 4);
  int* colsum     = (int*)alloc((size_t)nbkt * 4);
  int* bucket_base= (int*)alloc((size_t)(nbkt + 1) * 4);
  unsigned* bucketed = (unsigned*)alloc((size_t)E * 4);
  (void)ws_size; (void)n_in; (void)out_size;

  hipMemsetAsync(w + zoff, 0, zbytes, stream);

  const int nbN = (N + 255) / 256;
  const int total4 = N * FDIM / 4;
  const int gemmBlocks = (N + 63) / 64;
  const int nbW = (3 * FDIM * FDIM + 255) / 256;
  const int nodeChunks = (N + 63) / 64;   // 64 nodes per (chunk, p0-pair)
  const int gatherBlocks = nodeChunks * 8 + WARMB;
  const size_t pstride = (size_t)finishBlocks * FDIM;

  // stats + bounds + W^T + sentinel + edge bucket-histogram (no global atomics)
  k_bn<<<STATS_BLOCKS + nbN + nbW + 1 + nbH, 256, 0, stream>>>(
      x, partS, partQ, total4, batch, gstart, gend, gcn_w, W16T, H0, H1,
      esrc, edst, histA, E, nbN, nbW, N);
  k_scan<<<nbkt, 64, 0, stream>>>(histA, histOff, colsum, nbH, nbkt);
  k_aff<<<2, 256, 0, stream>>>(partS, partQ, gamma, beta, aff_a, aff_b,
                               gstart, gend, countsf, colsum, bucket_base, nbkt, N);
  k_scatter<<<nbH, 256, 0, stream>>>(esrc, edst, histOff, bucket_base, bucketed, E, nbkt);
  k_build<<<nbkt, 256, 0, stream>>>(bucketed, bucket_base, ell16, deg, dinv, N);
  // MFMA gemm0 (writes dinv-scaled H0)
  k_gemm0<<<gemmBlocks, 512, 0, stream>>>(x, aff_a, aff_b,
                                          (const _Float16*)W16T, (_Float16*)H0,
                                          dinv, N);

  // layer 0: gather from H0 (sliced, warmed), finish -> H1 via W1^T
  k_gather<<<gatherBlocks, 512, 0, stream>>>((const __half*)H0, Hagg16, S2SW,
                                             deg, ell16, gcn_b, w_att, dinv, N);
  k_finish<1><<<finishBlocks, 512, 0, stream>>>((const __half*)Hagg16, S2SW,
                                                (_Float16*)H1,
                                                (const _Float16*)(W16T + FDIM * FDIM),
                                                batch, dinv, wsum, msum, maxenc,
                                                wsP, msP, mxP, N);
  // layer 1: gather from H1, finish -> H0 via W2^T
  k_gather<<<gatherBlocks, 512, 0, stream>>>((const __half*)H1, Hagg16, S2SW,
                                             deg, ell16, gcn_b + FDIM, w_att + FDIM,
                                             dinv, N);
  k_finish<1><<<finishBlocks, 512, 0, stream>>>((const __half*)Hagg16, S2SW,
                                                (_Float16*)H0,
                                                (const _Float16*)(W16T + 2 * FDIM * FDIM),
                                                batch, dinv, wsum, msum,
                                                maxenc + (size_t)NGRAPH * FDIM,
                                                wsP + pstride, msP + pstride,
                                                mxP + pstride, N);
  // layer 2: gather from H0, finish (no epilogue)
  k_gather<<<gatherBlocks, 512, 0, stream>>>((const __half*)H0, Hagg16, S2SW,
                                             deg, ell16, gcn_b + 2 * FDIM,
                                             w_att + 2 * FDIM, dinv, N);
  k_finish<0><<<finishBlocks, 512, 0, stream>>>((const __half*)Hagg16, S2SW,
                                                nullptr, nullptr,
                                                batch, dinv, wsum, msum,
                                                maxenc + (size_t)2 * NGRAPH * FDIM,
                                                wsP + 2 * pstride, msP + 2 * pstride,
                                                mxP + 2 * pstride, N);
  k_head<<<NGRAPH, 128, 0, stream>>>(wsum, msum, maxenc, countsf,
                                     wsP, msP, mxP, finishBlocks, gstart, gend,
                                     l1w, l1b, l2w, l2b, out);
}